// Round 11
// baseline (214.140 us; speedup 1.0000x reference)
//
#include <hip/hip_runtime.h>
#include <stdint.h>

#define V      768
#define FINC   32
#define FOUTC  32
#define XYZ    512
#define NB     2
#define ROWP   40      // bf16 LDS row stride in ushorts (80 B)
#define MAXDEG 32
#define EROWS  40      // transposed-ELL rows incl. 8-deep addr-prefetch pad

typedef unsigned short u16;
typedef unsigned int   u32;
typedef short bf16x8 __attribute__((ext_vector_type(8)));
typedef float f32x4  __attribute__((ext_vector_type(4)));
typedef float f32x2  __attribute__((ext_vector_type(2)));

__device__ __forceinline__ u16 f2bf(float f) {
  u32 u = __float_as_uint(f);
  u32 r = u + 0x7fffu + ((u >> 16) & 1u);   // RNE
  return (u16)(r >> 16);
}
__device__ __forceinline__ float bflo(u32 w) { return __uint_as_float(w << 16); }
__device__ __forceinline__ float bfhi(u32 w) { return __uint_as_float(w & 0xffff0000u); }
// hi bf16 with low-16 mantissa garbage: <=2^-8 relative error, saves the AND
__device__ __forceinline__ float bfhi_raw(u32 w) { return __uint_as_float(w); }
__device__ __forceinline__ u32 cvtpk_bf16(float lo, float hi) {
  u32 r;
  asm("v_cvt_pk_bf16_f32 %0, %1, %2" : "=v"(r) : "v"(lo), "v"(hi));
  return r;
}

// ---------- kernel 1: deterministic ELL build, interleaved (col,val), zero-padded ----------
__global__ __launch_bounds__(64) void build_ell(const int* __restrict__ rows,
                                                const int* __restrict__ cols,
                                                const float* __restrict__ vals,
                                                int nnz,
                                                int2* __restrict__ epair,
                                                int* __restrict__ deg) {
  int v = blockIdx.x;
  int lane = threadIdx.x;
  int cnt = 0;
  for (int base = 0; base < nnz; base += 64) {
    int i = base + lane;
    bool m = (i < nnz) && (rows[i] == v);
    unsigned long long mask = __ballot(m);
    if (m) {
      int pos = cnt + __popcll(mask & ((1ull << lane) - 1ull));
      if (pos < MAXDEG)
        epair[v * MAXDEG + pos] = make_int2(cols[i], __float_as_int(vals[i]));
    }
    cnt += __popcll(mask);
  }
  int d = cnt < MAXDEG ? cnt : MAXDEG;
  for (int p = d + lane; p < MAXDEG; p += 64)
    epair[v * MAXDEG + p] = make_int2(0, 0);
  if (lane == 0) deg[v] = d;
}

// ---------- kernel 2: degree sort + SIMD-balanced placement + TRANSPOSED ELL ----------
__global__ __launch_bounds__(V) void sort_rows(const int2* __restrict__ epair,
                                               const int* __restrict__ deg,
                                               int2* __restrict__ ep3,     // [EROWS][V]
                                               int* __restrict__ perm,
                                               int* __restrict__ inv_g,
                                               int* __restrict__ wtrip) {
  __shared__ int sdeg[V];
  __shared__ u16 sinv[V];
  int v = threadIdx.x;
  int d = deg[v];
  sdeg[v] = d;
  __syncthreads();
  int r = 0;                       // rank (desc degree, tie v asc)
  for (int u = 0; u < V; ++u) {
    int du = sdeg[u];
    r += (du > d) || (du == d && u < v);
  }
  // group gr=r>>6 -> wave GINV[gr]; nibble-packed GINV = {0,1,2,3,7,11,6,10,5,9,4,8}
  const unsigned long long GPK = 0x8495A6B73210ull;
  int w = (int)((GPK >> (4 * (r >> 6))) & 15ull);
  int p = w * 64 + (r & 63);
  perm[p] = v;
  inv_g[v] = p;
  sinv[v] = (u16)p;
  if ((r & 63) == 0) wtrip[w] = d;
  __syncthreads();
  for (int e = 0; e < EROWS; ++e) {
    int2 o = make_int2(0, 0);
    if (e < d) {
      int2 pe = epair[v * MAXDEG + e];
      o = make_int2((int)sinv[pe.x] * (ROWP * 2), pe.y);   // bf16 CUR byte offset
    }
    ep3[e * V + p] = o;
  }
}

// ---------- kernel 3: x [B,Fin,V,XYZ] f32 -> xT [B,XYZ,pv,Fin] bf16 ----------
// LDS-tiled, both sides coalesced; float4 reads + cvt_pk_bf16.
#define TXV 12
__global__ __launch_bounds__(512) void transpose_x(const float* __restrict__ x,
                                                   const int* __restrict__ perm,
                                                   u16* __restrict__ xT) {
  __shared__ u32 TL2[384 * 34];   // [pair(row)][xyz2], stride 34 u32 -> 2-way-free banks
  __shared__ int PV[TXV];
  int g = blockIdx.x;             // b(2) x pvt(64) x xt(8)
  int b = g >> 9, pvt = (g >> 3) & 63, xt = g & 7;
  int pv0 = pvt * TXV;
  int xyz0 = xt * 64;
  int t = threadIdx.x;
  if (t < TXV) PV[t] = perm[pv0 + t];
  __syncthreads();
  int q = t & 15;                 // xyz quad: 4q..4q+3
  int rgrp = t >> 4;              // 0..31
#pragma unroll
  for (int st = 0; st < 12; ++st) {
    int row = st * 32 + rgrp;     // pair index 0..383 = vloc*32 + f
    int vloc = row >> 5, f = row & 31;
    const float4 xv = *(const float4*)&x[((size_t)(b * FINC + f) * V + PV[vloc]) * XYZ + xyz0 + 4 * q];
    u32 A = cvtpk_bf16(xv.x, xv.y);
    u32 B = cvtpk_bf16(xv.z, xv.w);
    *(uint2*)&TL2[row * 34 + 2 * q] = make_uint2(A, B);
  }
  __syncthreads();
  const u16* TL16 = (const u16*)TL2;   // row stride 68 u16
  int s = t & 7, xyz = t >> 3;
  u32* dst = (u32*)(xT + ((size_t)(b * XYZ + xyz0 + xyz) * V + pv0) * FINC);
#pragma unroll
  for (int it = 0; it < 24; ++it) {
    int i = s + 8 * it;           // u32 index 0..191
    u32 lo = TL16[(2 * i) * 68 + xyz];
    u32 hi = TL16[(2 * i + 1) * 68 + xyz];
    dst[i] = lo | (hi << 16);
  }
}

// ---------- kernel 4: fused recursion + MFMA GEMM; half-row 4-deep pipelined gather ----------
__global__ __launch_bounds__(1024, 4) void cheb_main(
    const u16* __restrict__ xT, const int2* __restrict__ ep3,
    const int* __restrict__ perm, const int* __restrict__ wtrip,
    const float* __restrict__ weight, const float* __restrict__ bias,
    u32* __restrict__ stage) {
  __shared__ __align__(16) u16   CUR[V * ROWP];   // 61440 B (T_k)
  __shared__ __align__(16) u16   PRV[V * ROWP];   // 61440 B (T_{k-1})
  __shared__ __align__(16) uint4 WF[5][2][64];    // 10240 B
  __shared__ u16 PRM[V];
  __shared__ int WT[12];

  int g = blockIdx.x;
  int xcd = g & 7;
  int u = g >> 3;
  int phase = u >> 5;
  int xyz = xcd * 32 + (u & 31) + (phase & 1) * 256;
  int b = phase >> 1;
  int slice = b * XYZ + xyz;

  int tid = threadIdx.x;
  int lane = tid & 63;
  int w = tid >> 6;               // wave 0..15
  int l15 = lane & 15, l4 = lane >> 4;
  bool gath = tid < V;            // waves 0..11 gather/own rows

  if (tid < 640) {
    int k = tid >> 7, n = (tid >> 6) & 1, ln = tid & 63;
    int a15 = ln & 15, a4 = ln >> 4;
    u32 pw[4];
#pragma unroll
    for (int p = 0; p < 4; ++p) {
      float w0 = weight[(size_t)(k * FINC + a4 * 8 + 2 * p) * FOUTC + n * 16 + a15];
      float w1 = weight[(size_t)(k * FINC + a4 * 8 + 2 * p + 1) * FOUTC + n * 16 + a15];
      pw[p] = (u32)f2bf(w0) | ((u32)f2bf(w1) << 16);
    }
    WF[k][n][ln] = make_uint4(pw[0], pw[1], pw[2], pw[3]);
  }
  if (tid < 12) WT[tid] = wtrip[tid];
  if (gath) PRM[tid] = (u16)perm[tid];
  float bsv[2] = {bias[l15], bias[16 + l15]};

  // ---- load permuted slice row tid into LDS (CUR only; PRV set in update 0)
  if (gath) {
    const uint4* src = (const uint4*)(xT + (size_t)slice * V * FINC) + tid * 4;
    uint4* dst = (uint4*)(CUR + tid * ROWP);
#pragma unroll
    for (int j = 0; j < 4; ++j) dst[j] = src[j];
  }
  __syncthreads();   // orders all xT reads before aliased stage writes at the end

  int trip = 0;
  if (w < 12) trip = __builtin_amdgcn_readfirstlane(WT[w]);
  const int2* pp = ep3 + tid;

  f32x4 acc[3][2];
#pragma unroll
  for (int a = 0; a < 3; ++a)
#pragma unroll
    for (int n = 0; n < 2; ++n) acc[a][n] = (f32x4){0.f, 0.f, 0.f, 0.f};

  // 16 waves x 48 rows each
  auto gemm_acc = [&](int k) {
    bf16x8 bn0 = *(const bf16x8*)&WF[k][0][lane];
    bf16x8 bn1 = *(const bf16x8*)&WF[k][1][lane];
#pragma unroll
    for (int a = 0; a < 3; ++a) {
      int row = w * 48 + a * 16 + l15;
      bf16x8 af = *(const bf16x8*)(CUR + row * ROWP + l4 * 8);
      acc[a][0] = __builtin_amdgcn_mfma_f32_16x16x32_bf16(af, bn0, acc[a][0], 0, 0, 0);
      acc[a][1] = __builtin_amdgcn_mfma_f32_16x16x32_bf16(af, bn1, acc[a][1], 0, 0, 0);
    }
  };

  // half-row gather: fa[8] (f32x2) covers cols h*16..h*16+15; 4-deep data ring,
  // 8-deep address ring; zero-padded edges are no-ops.
  f32x2 fa[8];
  auto fma_half = [&](float fv, uint4 qa, uint4 qb) {
    f32x2 fv2 = {fv, fv};
    u32 wq[8] = {qa.x, qa.y, qa.z, qa.w, qb.x, qb.y, qb.z, qb.w};
#pragma unroll
    for (int p = 0; p < 8; ++p) {
      f32x2 s = {bflo(wq[p]), bfhi_raw(wq[p])};
      fa[p] += fv2 * s;
    }
  };
  auto gather_half = [&](int h) {
#pragma unroll
    for (int j = 0; j < 8; ++j) fa[j] = (f32x2){0.f, 0.f};
    const char* base = (const char*)CUR + h * 32;
    int2 p0 = pp[0], p1 = pp[V], p2 = pp[2 * V], p3 = pp[3 * V];
    int2 a4 = pp[4 * V], a5 = pp[5 * V], a6 = pp[6 * V], a7 = pp[7 * V];
    const uint4* s;
    s = (const uint4*)(base + (u32)p0.x); uint4 D0a = s[0], D0b = s[1];
    s = (const uint4*)(base + (u32)p1.x); uint4 D1a = s[0], D1b = s[1];
    s = (const uint4*)(base + (u32)p2.x); uint4 D2a = s[0], D2b = s[1];
    s = (const uint4*)(base + (u32)p3.x); uint4 D3a = s[0], D3b = s[1];
    float v0 = __int_as_float(p0.y), v1 = __int_as_float(p1.y);
    float v2 = __int_as_float(p2.y), v3 = __int_as_float(p3.y);
    int tr = (trip + 3) & ~3;
    for (int e = 0; e < tr; e += 4) {
      int2 n0 = pp[(e + 8) * V], n1 = pp[(e + 9) * V];
      int2 n2 = pp[(e + 10) * V], n3 = pp[(e + 11) * V];
      fma_half(v0, D0a, D0b);
      s = (const uint4*)(base + (u32)a4.x); D0a = s[0]; D0b = s[1];
      v0 = __int_as_float(a4.y); a4 = n0;
      fma_half(v1, D1a, D1b);
      s = (const uint4*)(base + (u32)a5.x); D1a = s[0]; D1b = s[1];
      v1 = __int_as_float(a5.y); a5 = n1;
      fma_half(v2, D2a, D2b);
      s = (const uint4*)(base + (u32)a6.x); D2a = s[0]; D2b = s[1];
      v2 = __int_as_float(a6.y); a6 = n2;
      fma_half(v3, D3a, D3b);
      s = (const uint4*)(base + (u32)a7.x); D3a = s[0]; D3b = s[1];
      v3 = __int_as_float(a7.y); a7 = n3;
    }
  };

  // update: CUR=new T, PRV=old T. half0 from packed pk0 (bf16-rounded L·T), half1 from fa.
  u32 pk0[8];
  auto do_update = [&](bool first) {
    uint4* cp = (uint4*)(CUR + tid * ROWP);
    uint4* qp = (uint4*)(PRV + tid * ROWP);
    uint4 c0 = cp[0], c1 = cp[1], c2 = cp[2], c3 = cp[3];
    u32 n[16];
    if (first) {
#pragma unroll
      for (int j = 0; j < 8; ++j) n[j] = pk0[j];
#pragma unroll
      for (int j = 0; j < 8; ++j) n[8 + j] = cvtpk_bf16(fa[j][0], fa[j][1]);
    } else {
      uint4 q0 = qp[0], q1 = qp[1], q2 = qp[2], q3 = qp[3];
      u32 wp[16] = {q0.x, q0.y, q0.z, q0.w, q1.x, q1.y, q1.z, q1.w,
                    q2.x, q2.y, q2.z, q2.w, q3.x, q3.y, q3.z, q3.w};
#pragma unroll
      for (int j = 0; j < 8; ++j) {
        float lo = 2.f * bflo(pk0[j]) - bflo(wp[j]);
        float hi = 2.f * bfhi(pk0[j]) - bfhi(wp[j]);
        n[j] = cvtpk_bf16(lo, hi);
      }
#pragma unroll
      for (int j = 0; j < 8; ++j) {
        float lo = 2.f * fa[j][0] - bflo(wp[8 + j]);
        float hi = 2.f * fa[j][1] - bfhi(wp[8 + j]);
        n[8 + j] = cvtpk_bf16(lo, hi);
      }
    }
    qp[0] = c0; qp[1] = c1; qp[2] = c2; qp[3] = c3;
    cp[0] = make_uint4(n[0], n[1], n[2], n[3]);
    cp[1] = make_uint4(n[4], n[5], n[6], n[7]);
    cp[2] = make_uint4(n[8], n[9], n[10], n[11]);
    cp[3] = make_uint4(n[12], n[13], n[14], n[15]);
  };

  // ---- phases 0..3: gemm(T_k) ∥ gather(L*T_k) → barrier → update → barrier
#pragma unroll
  for (int ph = 0; ph <= 3; ++ph) {
    gemm_acc(ph);
    if (gath) {
      gather_half(0);
#pragma unroll
      for (int j = 0; j < 8; ++j) pk0[j] = cvtpk_bf16(fa[j][0], fa[j][1]);
      gather_half(1);
    }
    __syncthreads();
    if (gath) do_update(ph == 0);
    __syncthreads();
  }

  // ---- phase 4
  gemm_acc(4);

  // ---- epilogue: pack (fout, fout+16) per lane -> bf16 stage[slice][v][l15]
  u32* stg = stage + (size_t)slice * (V * 16);
#pragma unroll
  for (int a = 0; a < 3; ++a) {
#pragma unroll
    for (int r = 0; r < 4; ++r) {
      int vr = PRM[w * 48 + a * 16 + l4 * 4 + r];
      u32 pk = cvtpk_bf16(acc[a][0][r] + bsv[0], acc[a][1][r] + bsv[1]);
      stg[vr * 16 + l15] = pk;
    }
  }
}

// ---------- kernel 5: stage [b][xyz][v][f2] bf16 -> out [b][fout][v][xyz] f32 ----------
#define TO_VT  12
#define TO_PAD 193
__global__ __launch_bounds__(512) void transpose_out(const u32* __restrict__ stage,
                                                     float* __restrict__ out) {
  __shared__ u32 T[64 * TO_PAD];   // 49.4 KB -> 2 blocks/CU
  int g = blockIdx.x;              // b(2) x vt(64) x xt(8)
  int b = g >> 9, vt = (g >> 3) & 63, xt = g & 7;
  int v0 = vt * TO_VT;
  int xyz0 = xt * 64;
  int t = threadIdx.x;
  const u32* base = stage + (size_t)(b * XYZ + xyz0) * (V * 16) + v0 * 16;
#pragma unroll
  for (int i = 0; i < 6; ++i) {
    int idx4 = i * 512 + t;
    int j = idx4 / 48;
    int c4 = idx4 - j * 48;
    uint4 q = *(const uint4*)(base + (size_t)j * (V * 16) + c4 * 4);
    int w0 = c4 * 4;
    T[j * TO_PAD + w0]     = q.x;
    T[j * TO_PAD + w0 + 1] = q.y;
    T[j * TO_PAD + w0 + 2] = q.z;
    T[j * TO_PAD + w0 + 3] = q.w;
  }
  __syncthreads();
  int xyz2 = t & 31;               // xyz pair: 2*xyz2, 2*xyz2+1
  int grp = t >> 5;                // 0..15
#pragma unroll
  for (int i = 0; i < 24; ++i) {
    int fout = grp * 2 + (i & 1);
    int vv = i >> 1;
    int col = vv * 16 + (fout & 15);
    u32 pka = T[(2 * xyz2) * TO_PAD + col];
    u32 pkb = T[(2 * xyz2 + 1) * TO_PAD + col];
    float va = (fout < 16) ? bflo(pka) : bfhi(pka);
    float vb = (fout < 16) ? bflo(pkb) : bfhi(pkb);
    *(float2*)&out[((size_t)(b * FOUTC + fout) * V + v0 + vv) * XYZ + xyz0 + 2 * xyz2] =
        make_float2(va, vb);
  }
}

extern "C" void kernel_launch(void* const* d_in, const int* in_sizes, int n_in,
                              void* d_out, int out_size, void* d_ws, size_t ws_size,
                              hipStream_t stream) {
  const int*   lap_rows = (const int*)d_in[0];
  const int*   lap_cols = (const int*)d_in[1];
  const float* lap_vals = (const float*)d_in[2];
  const float* x        = (const float*)d_in[3];
  const float* weight   = (const float*)d_in[4];
  const float* bias     = (const float*)d_in[5];
  float* out = (float*)d_out;
  int nnz = in_sizes[0];

  char* ws = (char*)d_ws;
  const size_t XT_BYTES = (size_t)NB * XYZ * V * FINC * sizeof(u16);  // 50,331,648
  const size_t EP_BYTES = (size_t)V * MAXDEG * 8;                     // 196,608
  const size_t E3_BYTES = (size_t)EROWS * V * 8;                      // 245,760
  u16*  xT    = (u16*)ws;                // aliased: bf16 stage [b][xyz][v][f2]
  u32*  stg   = (u32*)ws;
  int2* epair = (int2*)(ws + XT_BYTES);
  int2* ep3   = (int2*)(ws + XT_BYTES + EP_BYTES);
  int*  deg   = (int*)(ws + XT_BYTES + EP_BYTES + E3_BYTES);
  int*  perm  = (int*)(ws + XT_BYTES + EP_BYTES + E3_BYTES + 3072);
  int*  inv_g = (int*)(ws + XT_BYTES + EP_BYTES + E3_BYTES + 6144);
  int*  wtrip = (int*)(ws + XT_BYTES + EP_BYTES + E3_BYTES + 9216);

  hipLaunchKernelGGL(build_ell, dim3(V), dim3(64), 0, stream,
                     lap_rows, lap_cols, lap_vals, nnz, epair, deg);
  hipLaunchKernelGGL(sort_rows, dim3(1), dim3(V), 0, stream,
                     epair, deg, ep3, perm, inv_g, wtrip);
  hipLaunchKernelGGL(transpose_x, dim3(NB * 64 * 8), dim3(512), 0, stream,
                     x, perm, xT);
  hipLaunchKernelGGL(cheb_main, dim3(NB * XYZ), dim3(1024), 0, stream,
                     xT, ep3, perm, wtrip, weight, bias, stg);
  hipLaunchKernelGGL(transpose_out, dim3(NB * 64 * 8), dim3(512), 0, stream,
                     stg, out);
}

// Round 12
// 193.629 us; speedup vs baseline: 1.1059x; 1.1059x over previous
//
#include <hip/hip_runtime.h>
#include <stdint.h>

#define V      768
#define FINC   32
#define FOUTC  32
#define XYZ    512
#define NB     2
#define ROWP   40      // bf16 LDS row stride in ushorts (80 B)
#define MAXDEG 32
#define EROWS  36      // transposed-ELL rows incl. 4-deep prefetch pad

typedef unsigned short u16;
typedef unsigned int   u32;
typedef short bf16x8 __attribute__((ext_vector_type(8)));
typedef float f32x4  __attribute__((ext_vector_type(4)));
typedef float f32x2  __attribute__((ext_vector_type(2)));

__device__ __forceinline__ u16 f2bf(float f) {
  u32 u = __float_as_uint(f);
  u32 r = u + 0x7fffu + ((u >> 16) & 1u);   // RNE
  return (u16)(r >> 16);
}
__device__ __forceinline__ float bflo(u32 w) { return __uint_as_float(w << 16); }
__device__ __forceinline__ float bfhi(u32 w) { return __uint_as_float(w & 0xffff0000u); }
// hi bf16 with low-16 mantissa garbage: <=2^-8 relative error, saves the AND
__device__ __forceinline__ float bfhi_raw(u32 w) { return __uint_as_float(w); }
__device__ __forceinline__ u32 cvtpk_bf16(float lo, float hi) {
  u32 r;
  asm("v_cvt_pk_bf16_f32 %0, %1, %2" : "=v"(r) : "v"(lo), "v"(hi));
  return r;
}

// ---------- kernel 1: deterministic ELL build, interleaved (col,val), zero-padded ----------
__global__ __launch_bounds__(64) void build_ell(const int* __restrict__ rows,
                                                const int* __restrict__ cols,
                                                const float* __restrict__ vals,
                                                int nnz,
                                                int2* __restrict__ epair,
                                                int* __restrict__ deg) {
  int v = blockIdx.x;
  int lane = threadIdx.x;
  int cnt = 0;
  for (int base = 0; base < nnz; base += 64) {
    int i = base + lane;
    bool m = (i < nnz) && (rows[i] == v);
    unsigned long long mask = __ballot(m);
    if (m) {
      int pos = cnt + __popcll(mask & ((1ull << lane) - 1ull));
      if (pos < MAXDEG)
        epair[v * MAXDEG + pos] = make_int2(cols[i], __float_as_int(vals[i]));
    }
    cnt += __popcll(mask);
  }
  int d = cnt < MAXDEG ? cnt : MAXDEG;
  for (int p = d + lane; p < MAXDEG; p += 64)
    epair[v * MAXDEG + p] = make_int2(0, 0);
  if (lane == 0) deg[v] = d;
}

// ---------- kernel 2: degree sort + SIMD-balanced placement (rank/perm only) ----------
__global__ __launch_bounds__(V) void sort_rows(const int* __restrict__ deg,
                                               int* __restrict__ perm,
                                               int* __restrict__ inv_g,
                                               int* __restrict__ wtrip) {
  __shared__ int sdeg[V];
  int v = threadIdx.x;
  int d = deg[v];
  sdeg[v] = d;
  __syncthreads();
  int r = 0;                       // rank (desc degree, tie v asc)
  for (int u = 0; u < V; ++u) {
    int du = sdeg[u];
    r += (du > d) || (du == d && u < v);
  }
  // group gr=r>>6 -> wave GINV[gr]; nibble-packed GINV = {0,1,2,3,7,11,6,10,5,9,4,8}
  const unsigned long long GPK = 0x8495A6B73210ull;
  int w = (int)((GPK >> (4 * (r >> 6))) & 15ull);
  int p = w * 64 + (r & 63);
  perm[p] = v;
  inv_g[v] = p;
  if ((r & 63) == 0) wtrip[w] = d;
}

// ---------- kernel 3: x [B,Fin,V,XYZ] f32 -> xT [B,XYZ,pv,Fin] bf16 ----------
// LDS-tiled, both sides coalesced; float4 reads + cvt_pk_bf16.
// First EROWS blocks additionally build one transposed-ELL row each (coalesced
// over placements; scattered reads spread across 36 CUs instead of 1).
#define TXV 12
__global__ __launch_bounds__(512) void transpose_x(const float* __restrict__ x,
                                                   const int* __restrict__ perm,
                                                   const int* __restrict__ deg,
                                                   const int2* __restrict__ epair,
                                                   const int* __restrict__ inv_g,
                                                   int2* __restrict__ ep3,
                                                   u16* __restrict__ xT) {
  __shared__ u32 TL2[384 * 34];   // [pair(row)][xyz2], stride 34 u32 -> 2-way-free banks
  __shared__ int PV[TXV];
  int g = blockIdx.x;             // b(2) x pvt(64) x xt(8)
  int t = threadIdx.x;
  if (g < EROWS) {                // side-job: build ep3 row e=g
    int e = g;
    for (int p = t; p < V; p += 512) {
      int v = perm[p];
      int d = deg[v];
      int2 o = make_int2(0, 0);
      if (e < d) {                // e<d<=32 keeps epair access in-bounds
        int2 pe = epair[v * MAXDEG + e];
        o = make_int2(inv_g[pe.x] * (ROWP * 2), pe.y);
      }
      ep3[e * V + p] = o;         // coalesced over p
    }
  }
  int b = g >> 9, pvt = (g >> 3) & 63, xt = g & 7;
  int pv0 = pvt * TXV;
  int xyz0 = xt * 64;
  if (t < TXV) PV[t] = perm[pv0 + t];
  __syncthreads();
  int q = t & 15;                 // xyz quad: 4q..4q+3
  int rgrp = t >> 4;              // 0..31
#pragma unroll
  for (int st = 0; st < 12; ++st) {
    int row = st * 32 + rgrp;     // pair index 0..383 = vloc*32 + f
    int vloc = row >> 5, f = row & 31;
    const float4 xv = *(const float4*)&x[((size_t)(b * FINC + f) * V + PV[vloc]) * XYZ + xyz0 + 4 * q];
    u32 A = cvtpk_bf16(xv.x, xv.y);
    u32 B = cvtpk_bf16(xv.z, xv.w);
    *(uint2*)&TL2[row * 34 + 2 * q] = make_uint2(A, B);
  }
  __syncthreads();
  const u16* TL16 = (const u16*)TL2;   // row stride 68 u16
  int s = t & 7, xyz = t >> 3;
  u32* dst = (u32*)(xT + ((size_t)(b * XYZ + xyz0 + xyz) * V + pv0) * FINC);
#pragma unroll
  for (int it = 0; it < 24; ++it) {
    int i = s + 8 * it;           // u32 index 0..191
    u32 lo = TL16[(2 * i) * 68 + xyz];
    u32 hi = TL16[(2 * i + 1) * 68 + xyz];
    dst[i] = lo | (hi << 16);
  }
}

// ---------- kernel 4: fused recursion + MFMA GEMM; software-pipelined gather (r10) ----------
__global__ __launch_bounds__(1024, 4) void cheb_main(
    const u16* __restrict__ xT, const int2* __restrict__ ep3,
    const int* __restrict__ perm, const int* __restrict__ wtrip,
    const float* __restrict__ weight, const float* __restrict__ bias,
    u32* __restrict__ stage) {
  __shared__ __align__(16) u16   CUR[V * ROWP];   // 61440 B (T_k)
  __shared__ __align__(16) u16   PRV[V * ROWP];   // 61440 B (T_{k-1})
  __shared__ __align__(16) uint4 WF[5][2][64];    // 10240 B
  __shared__ u16 PRM[V];
  __shared__ int WT[12];

  int g = blockIdx.x;
  int xcd = g & 7;
  int u = g >> 3;
  int phase = u >> 5;
  int xyz = xcd * 32 + (u & 31) + (phase & 1) * 256;
  int b = phase >> 1;
  int slice = b * XYZ + xyz;

  int tid = threadIdx.x;
  int lane = tid & 63;
  int w = tid >> 6;               // wave 0..15
  int l15 = lane & 15, l4 = lane >> 4;
  bool gath = tid < V;            // waves 0..11 gather/own rows

  if (tid < 640) {
    int k = tid >> 7, n = (tid >> 6) & 1, ln = tid & 63;
    int a15 = ln & 15, a4 = ln >> 4;
    u32 pw[4];
#pragma unroll
    for (int p = 0; p < 4; ++p) {
      float w0 = weight[(size_t)(k * FINC + a4 * 8 + 2 * p) * FOUTC + n * 16 + a15];
      float w1 = weight[(size_t)(k * FINC + a4 * 8 + 2 * p + 1) * FOUTC + n * 16 + a15];
      pw[p] = (u32)f2bf(w0) | ((u32)f2bf(w1) << 16);
    }
    WF[k][n][ln] = make_uint4(pw[0], pw[1], pw[2], pw[3]);
  }
  if (tid < 12) WT[tid] = wtrip[tid];
  if (gath) PRM[tid] = (u16)perm[tid];
  float bsv[2] = {bias[l15], bias[16 + l15]};

  // ---- load permuted slice row tid into LDS (CUR only; PRV set in update 0)
  if (gath) {
    const uint4* src = (const uint4*)(xT + (size_t)slice * V * FINC) + tid * 4;
    uint4* dst = (uint4*)(CUR + tid * ROWP);
#pragma unroll
    for (int j = 0; j < 4; ++j) dst[j] = src[j];
  }
  __syncthreads();   // orders all xT reads before aliased stage writes at the end

  int trip = 0;
  if (w < 12) trip = __builtin_amdgcn_readfirstlane(WT[w]);
  const int2* pp = ep3 + tid;

  f32x4 acc[3][2];
#pragma unroll
  for (int a = 0; a < 3; ++a)
#pragma unroll
    for (int n = 0; n < 2; ++n) acc[a][n] = (f32x4){0.f, 0.f, 0.f, 0.f};

  // 16 waves x 48 rows each
  auto gemm_acc = [&](int k) {
    bf16x8 bn0 = *(const bf16x8*)&WF[k][0][lane];
    bf16x8 bn1 = *(const bf16x8*)&WF[k][1][lane];
#pragma unroll
    for (int a = 0; a < 3; ++a) {
      int row = w * 48 + a * 16 + l15;
      bf16x8 af = *(const bf16x8*)(CUR + row * ROWP + l4 * 8);
      acc[a][0] = __builtin_amdgcn_mfma_f32_16x16x32_bf16(af, bn0, acc[a][0], 0, 0, 0);
      acc[a][1] = __builtin_amdgcn_mfma_f32_16x16x32_bf16(af, bn1, acc[a][1], 0, 0, 0);
    }
  };

  // fa2 = (L * CUR)[tid,:] — software-pipelined: issue edge e+1 reads, FMA edge e.
  f32x2 fa2[16];
  auto fma_edge = [&](float fv, uint4 qa, uint4 qb, uint4 qc, uint4 qd) {
    f32x2 fv2 = {fv, fv};
    u32 wq[16] = {qa.x, qa.y, qa.z, qa.w, qb.x, qb.y, qb.z, qb.w,
                  qc.x, qc.y, qc.z, qc.w, qd.x, qd.y, qd.z, qd.w};
#pragma unroll
    for (int p = 0; p < 16; ++p) {
      f32x2 s = {bflo(wq[p]), bfhi_raw(wq[p])};   // raw hi: <=2^-8 rel noise
      fa2[p] += fv2 * s;
    }
  };
  auto gather = [&]() {
#pragma unroll
    for (int j = 0; j < 16; ++j) fa2[j] = (f32x2){0.f, 0.f};
    int trips = (trip + 1) & ~1;                  // even; padded edges have val 0
    int2 r0 = pp[0], r1 = pp[V], r2 = pp[2 * V];  // pair ring (e, e+1, e+2)
    const uint4* s0 = (const uint4*)((const char*)CUR + (u32)r0.x);
    uint4 A0 = s0[0], A1 = s0[1], A2 = s0[2], A3 = s0[3];
    for (int e = 0; e < trips; e += 2) {
      const uint4* s1 = (const uint4*)((const char*)CUR + (u32)r1.x);
      uint4 B0 = s1[0], B1 = s1[1], B2 = s1[2], B3 = s1[3];  // issue edge e+1
      int2 n3 = pp[(e + 3) * V];
      fma_edge(__int_as_float(r0.y), A0, A1, A2, A3);        // consume edge e
      const uint4* s2 = (const uint4*)((const char*)CUR + (u32)r2.x);
      A0 = s2[0]; A1 = s2[1]; A2 = s2[2]; A3 = s2[3];        // issue edge e+2
      int2 n4 = pp[(e + 4) * V];
      fma_edge(__int_as_float(r1.y), B0, B1, B2, B3);        // consume edge e+1
      r0 = r2; r1 = n3; r2 = n4;
    }
  };

  // update: CUR=new T, PRV=old T.  first: T1=fa2; else: T_{k+1}=2*fa2-PRV
  auto do_update = [&](bool first) {
    uint4* cp = (uint4*)(CUR + tid * ROWP);
    uint4* qp = (uint4*)(PRV + tid * ROWP);
    uint4 c[4];
#pragma unroll
    for (int j = 0; j < 4; ++j) c[j] = cp[j];
    u32 npk[16];
    if (first) {
#pragma unroll
      for (int j = 0; j < 16; ++j) npk[j] = cvtpk_bf16(fa2[j][0], fa2[j][1]);
    } else {
      uint4 pv[4];
#pragma unroll
      for (int j = 0; j < 4; ++j) pv[j] = qp[j];
      u32 wp[16] = {pv[0].x, pv[0].y, pv[0].z, pv[0].w, pv[1].x, pv[1].y, pv[1].z, pv[1].w,
                    pv[2].x, pv[2].y, pv[2].z, pv[2].w, pv[3].x, pv[3].y, pv[3].z, pv[3].w};
#pragma unroll
      for (int j = 0; j < 16; ++j) {
        float t0 = 2.f * fa2[j][0] - bflo(wp[j]);
        float t1 = 2.f * fa2[j][1] - bfhi(wp[j]);
        npk[j] = cvtpk_bf16(t0, t1);
      }
    }
#pragma unroll
    for (int j = 0; j < 4; ++j) {
      qp[j] = c[j];                               // PRV = old T
      cp[j] = make_uint4(npk[4 * j], npk[4 * j + 1], npk[4 * j + 2], npk[4 * j + 3]);
    }
  };

  // ---- phases 0..3: gemm(T_k) ∥ gather(L*T_k) → barrier → update → barrier
#pragma unroll
  for (int ph = 0; ph <= 3; ++ph) {
    gemm_acc(ph);
    if (gath) gather();
    __syncthreads();
    if (gath) do_update(ph == 0);
    __syncthreads();
  }

  // ---- phase 4
  gemm_acc(4);

  // ---- epilogue: pack (fout, fout+16) per lane -> bf16 stage[slice][v][l15]
  u32* stg = stage + (size_t)slice * (V * 16);
#pragma unroll
  for (int a = 0; a < 3; ++a) {
#pragma unroll
    for (int r = 0; r < 4; ++r) {
      int vr = PRM[w * 48 + a * 16 + l4 * 4 + r];
      u32 pk = cvtpk_bf16(acc[a][0][r] + bsv[0], acc[a][1][r] + bsv[1]);
      stg[vr * 16 + l15] = pk;
    }
  }
}

// ---------- kernel 5: stage [b][xyz][v][f2] bf16 -> out [b][fout][v][xyz] f32 ----------
#define TO_VT  12
#define TO_PAD 193
__global__ __launch_bounds__(512) void transpose_out(const u32* __restrict__ stage,
                                                     float* __restrict__ out) {
  __shared__ u32 T[64 * TO_PAD];   // 49.4 KB -> 2 blocks/CU
  int g = blockIdx.x;              // b(2) x vt(64) x xt(8)
  int b = g >> 9, vt = (g >> 3) & 63, xt = g & 7;
  int v0 = vt * TO_VT;
  int xyz0 = xt * 64;
  int t = threadIdx.x;
  const u32* base = stage + (size_t)(b * XYZ + xyz0) * (V * 16) + v0 * 16;
#pragma unroll
  for (int i = 0; i < 6; ++i) {
    int idx4 = i * 512 + t;
    int j = idx4 / 48;
    int c4 = idx4 - j * 48;
    uint4 q = *(const uint4*)(base + (size_t)j * (V * 16) + c4 * 4);
    int w0 = c4 * 4;
    T[j * TO_PAD + w0]     = q.x;
    T[j * TO_PAD + w0 + 1] = q.y;
    T[j * TO_PAD + w0 + 2] = q.z;
    T[j * TO_PAD + w0 + 3] = q.w;
  }
  __syncthreads();
  int xyz2 = t & 31;               // xyz pair: 2*xyz2, 2*xyz2+1
  int grp = t >> 5;                // 0..15
#pragma unroll
  for (int i = 0; i < 24; ++i) {
    int fout = grp * 2 + (i & 1);
    int vv = i >> 1;
    int col = vv * 16 + (fout & 15);
    u32 pka = T[(2 * xyz2) * TO_PAD + col];
    u32 pkb = T[(2 * xyz2 + 1) * TO_PAD + col];
    float va = (fout < 16) ? bflo(pka) : bfhi(pka);
    float vb = (fout < 16) ? bflo(pkb) : bfhi(pkb);
    *(float2*)&out[((size_t)(b * FOUTC + fout) * V + v0 + vv) * XYZ + xyz0 + 2 * xyz2] =
        make_float2(va, vb);
  }
}

extern "C" void kernel_launch(void* const* d_in, const int* in_sizes, int n_in,
                              void* d_out, int out_size, void* d_ws, size_t ws_size,
                              hipStream_t stream) {
  const int*   lap_rows = (const int*)d_in[0];
  const int*   lap_cols = (const int*)d_in[1];
  const float* lap_vals = (const float*)d_in[2];
  const float* x        = (const float*)d_in[3];
  const float* weight   = (const float*)d_in[4];
  const float* bias     = (const float*)d_in[5];
  float* out = (float*)d_out;
  int nnz = in_sizes[0];

  char* ws = (char*)d_ws;
  const size_t XT_BYTES = (size_t)NB * XYZ * V * FINC * sizeof(u16);  // 50,331,648
  const size_t EP_BYTES = (size_t)V * MAXDEG * 8;                     // 196,608
  const size_t E3_BYTES = (size_t)EROWS * V * 8;                      // 221,184
  u16*  xT    = (u16*)ws;                // aliased: bf16 stage [b][xyz][v][f2]
  u32*  stg   = (u32*)ws;
  int2* epair = (int2*)(ws + XT_BYTES);
  int2* ep3   = (int2*)(ws + XT_BYTES + EP_BYTES);
  int*  deg   = (int*)(ws + XT_BYTES + EP_BYTES + E3_BYTES);
  int*  perm  = (int*)(ws + XT_BYTES + EP_BYTES + E3_BYTES + 3072);
  int*  inv_g = (int*)(ws + XT_BYTES + EP_BYTES + E3_BYTES + 6144);
  int*  wtrip = (int*)(ws + XT_BYTES + EP_BYTES + E3_BYTES + 9216);

  hipLaunchKernelGGL(build_ell, dim3(V), dim3(64), 0, stream,
                     lap_rows, lap_cols, lap_vals, nnz, epair, deg);
  hipLaunchKernelGGL(sort_rows, dim3(1), dim3(V), 0, stream,
                     deg, perm, inv_g, wtrip);
  hipLaunchKernelGGL(transpose_x, dim3(NB * 64 * 8), dim3(512), 0, stream,
                     x, perm, deg, epair, inv_g, ep3, xT);
  hipLaunchKernelGGL(cheb_main, dim3(NB * XYZ), dim3(1024), 0, stream,
                     xT, ep3, perm, wtrip, weight, bias, stg);
  hipLaunchKernelGGL(transpose_out, dim3(NB * 64 * 8), dim3(512), 0, stream,
                     stg, out);
}

// Round 13
// 185.568 us; speedup vs baseline: 1.1540x; 1.0434x over previous
//
#include <hip/hip_runtime.h>
#include <stdint.h>

#define V      768
#define FINC   32
#define FOUTC  32
#define XYZ    512
#define NB     2
#define ROWP   40      // bf16 LDS row stride in ushorts (80 B)
#define MAXDEG 32
#define EROWS  36      // transposed-ELL rows incl. 4-deep prefetch pad

typedef unsigned short u16;
typedef unsigned int   u32;
typedef short bf16x8 __attribute__((ext_vector_type(8)));
typedef float f32x4  __attribute__((ext_vector_type(4)));
typedef float f32x2  __attribute__((ext_vector_type(2)));

__device__ __forceinline__ u16 f2bf(float f) {
  u32 u = __float_as_uint(f);
  u32 r = u + 0x7fffu + ((u >> 16) & 1u);   // RNE
  return (u16)(r >> 16);
}
__device__ __forceinline__ float bflo(u32 w) { return __uint_as_float(w << 16); }
__device__ __forceinline__ float bfhi(u32 w) { return __uint_as_float(w & 0xffff0000u); }
// hi bf16 with low-16 mantissa garbage: <=2^-8 relative error, saves the AND
__device__ __forceinline__ float bfhi_raw(u32 w) { return __uint_as_float(w); }
__device__ __forceinline__ u32 cvtpk_bf16(float lo, float hi) {
  u32 r;
  asm("v_cvt_pk_bf16_f32 %0, %1, %2" : "=v"(r) : "v"(lo), "v"(hi));
  return r;
}

// ---------- kernel 1: deterministic ELL build, interleaved (col,val), zero-padded ----------
__global__ __launch_bounds__(64) void build_ell(const int* __restrict__ rows,
                                                const int* __restrict__ cols,
                                                const float* __restrict__ vals,
                                                int nnz,
                                                int2* __restrict__ epair,
                                                int* __restrict__ deg) {
  int v = blockIdx.x;
  int lane = threadIdx.x;
  int cnt = 0;
  for (int base = 0; base < nnz; base += 64) {
    int i = base + lane;
    bool m = (i < nnz) && (rows[i] == v);
    unsigned long long mask = __ballot(m);
    if (m) {
      int pos = cnt + __popcll(mask & ((1ull << lane) - 1ull));
      if (pos < MAXDEG)
        epair[v * MAXDEG + pos] = make_int2(cols[i], __float_as_int(vals[i]));
    }
    cnt += __popcll(mask);
  }
  int d = cnt < MAXDEG ? cnt : MAXDEG;
  for (int p = d + lane; p < MAXDEG; p += 64)
    epair[v * MAXDEG + p] = make_int2(0, 0);
  if (lane == 0) deg[v] = d;
}

// ---------- kernel 2: degree sort + SIMD-balanced placement (rank/perm only) ----------
__global__ __launch_bounds__(V) void sort_rows(const int* __restrict__ deg,
                                               int* __restrict__ perm,
                                               int* __restrict__ inv_g,
                                               int* __restrict__ wtrip) {
  __shared__ int sdeg[V];
  int v = threadIdx.x;
  int d = deg[v];
  sdeg[v] = d;
  __syncthreads();
  int r = 0;                       // rank (desc degree, tie v asc)
  for (int u = 0; u < V; ++u) {
    int du = sdeg[u];
    r += (du > d) || (du == d && u < v);
  }
  // group gr=r>>6 -> wave GINV[gr]; nibble-packed GINV = {0,1,2,3,7,11,6,10,5,9,4,8}
  const unsigned long long GPK = 0x8495A6B73210ull;
  int w = (int)((GPK >> (4 * (r >> 6))) & 15ull);
  int p = w * 64 + (r & 63);
  perm[p] = v;
  inv_g[v] = p;
  if ((r & 63) == 0) wtrip[w] = d;
}

// ---------- kernel 3: x [B,Fin,V,XYZ] f32 -> xT [B,XYZ,pv,Fin] bf16 ----------
// LDS-tiled, both sides coalesced; float4 reads + cvt_pk_bf16.
// First EROWS blocks additionally build one transposed-ELL row each.
#define TXV 12
__global__ __launch_bounds__(512) void transpose_x(const float* __restrict__ x,
                                                   const int* __restrict__ perm,
                                                   const int* __restrict__ deg,
                                                   const int2* __restrict__ epair,
                                                   const int* __restrict__ inv_g,
                                                   int2* __restrict__ ep3,
                                                   u16* __restrict__ xT) {
  __shared__ u32 TL2[384 * 34];   // [pair(row)][xyz2], stride 34 u32 -> 2-way-free banks
  __shared__ int PV[TXV];
  int g = blockIdx.x;             // b(2) x pvt(64) x xt(8)
  int t = threadIdx.x;
  if (g < EROWS) {                // side-job: build ep3 row e=g
    int e = g;
    for (int p = t; p < V; p += 512) {
      int v = perm[p];
      int d = deg[v];
      int2 o = make_int2(0, 0);
      if (e < d) {                // e<d<=32 keeps epair access in-bounds
        int2 pe = epair[v * MAXDEG + e];
        o = make_int2(inv_g[pe.x] * (ROWP * 2), pe.y);
      }
      ep3[e * V + p] = o;         // coalesced over p
    }
  }
  int b = g >> 9, pvt = (g >> 3) & 63, xt = g & 7;
  int pv0 = pvt * TXV;
  int xyz0 = xt * 64;
  if (t < TXV) PV[t] = perm[pv0 + t];
  __syncthreads();
  int q = t & 15;                 // xyz quad: 4q..4q+3
  int rgrp = t >> 4;              // 0..31
#pragma unroll
  for (int st = 0; st < 12; ++st) {
    int row = st * 32 + rgrp;     // pair index 0..383 = vloc*32 + f
    int vloc = row >> 5, f = row & 31;
    const float4 xv = *(const float4*)&x[((size_t)(b * FINC + f) * V + PV[vloc]) * XYZ + xyz0 + 4 * q];
    u32 A = cvtpk_bf16(xv.x, xv.y);
    u32 B = cvtpk_bf16(xv.z, xv.w);
    *(uint2*)&TL2[row * 34 + 2 * q] = make_uint2(A, B);
  }
  __syncthreads();
  const u16* TL16 = (const u16*)TL2;   // row stride 68 u16
  int s = t & 7, xyz = t >> 3;
  u32* dst = (u32*)(xT + ((size_t)(b * XYZ + xyz0 + xyz) * V + pv0) * FINC);
#pragma unroll
  for (int it = 0; it < 24; ++it) {
    int i = s + 8 * it;           // u32 index 0..191
    u32 lo = TL16[(2 * i) * 68 + xyz];
    u32 hi = TL16[(2 * i + 1) * 68 + xyz];
    dst[i] = lo | (hi << 16);
  }
}

// ---------- kernel 4: fused recursion + MFMA GEMM; ping-pong buffers, 1 barrier/phase ----------
__global__ __launch_bounds__(1024, 4) void cheb_main(
    const u16* __restrict__ xT, const int2* __restrict__ ep3,
    const int* __restrict__ perm, const int* __restrict__ wtrip,
    const float* __restrict__ weight, const float* __restrict__ bias,
    u32* __restrict__ stage) {
  __shared__ __align__(16) u16   TA[V * ROWP];    // 61440 B
  __shared__ __align__(16) u16   TB[V * ROWP];    // 61440 B
  __shared__ __align__(16) uint4 WF[5][2][64];    // 10240 B
  __shared__ u16 PRM[V];
  __shared__ int WT[12];

  int g = blockIdx.x;
  int xcd = g & 7;
  int u = g >> 3;
  int phase = u >> 5;
  int xyz = xcd * 32 + (u & 31) + (phase & 1) * 256;
  int b = phase >> 1;
  int slice = b * XYZ + xyz;

  int tid = threadIdx.x;
  int lane = tid & 63;
  int w = tid >> 6;               // wave 0..15
  int l15 = lane & 15, l4 = lane >> 4;
  bool gath = tid < V;            // waves 0..11 gather/own rows

  if (tid < 640) {
    int k = tid >> 7, n = (tid >> 6) & 1, ln = tid & 63;
    int a15 = ln & 15, a4 = ln >> 4;
    u32 pw[4];
#pragma unroll
    for (int p = 0; p < 4; ++p) {
      float w0 = weight[(size_t)(k * FINC + a4 * 8 + 2 * p) * FOUTC + n * 16 + a15];
      float w1 = weight[(size_t)(k * FINC + a4 * 8 + 2 * p + 1) * FOUTC + n * 16 + a15];
      pw[p] = (u32)f2bf(w0) | ((u32)f2bf(w1) << 16);
    }
    WF[k][n][ln] = make_uint4(pw[0], pw[1], pw[2], pw[3]);
  }
  if (tid < 12) WT[tid] = wtrip[tid];
  if (gath) PRM[tid] = (u16)perm[tid];
  float bsv[2] = {bias[l15], bias[16 + l15]};

  // ---- load permuted slice row tid into TA (T0)
  if (gath) {
    const uint4* src = (const uint4*)(xT + (size_t)slice * V * FINC) + tid * 4;
    uint4* dst = (uint4*)(TA + tid * ROWP);
#pragma unroll
    for (int j = 0; j < 4; ++j) dst[j] = src[j];
  }
  __syncthreads();   // orders all xT reads before aliased stage writes at the end

  int trip = 0;
  if (w < 12) trip = __builtin_amdgcn_readfirstlane(WT[w]);
  const int2* pp = ep3 + tid;

  f32x4 acc[3][2];
#pragma unroll
  for (int a = 0; a < 3; ++a)
#pragma unroll
    for (int n = 0; n < 2; ++n) acc[a][n] = (f32x4){0.f, 0.f, 0.f, 0.f};

  // 16 waves x 48 rows each
  auto gemm_acc = [&](const u16* T, int k) {
    bf16x8 bn0 = *(const bf16x8*)&WF[k][0][lane];
    bf16x8 bn1 = *(const bf16x8*)&WF[k][1][lane];
#pragma unroll
    for (int a = 0; a < 3; ++a) {
      int row = w * 48 + a * 16 + l15;
      bf16x8 af = *(const bf16x8*)(T + row * ROWP + l4 * 8);
      acc[a][0] = __builtin_amdgcn_mfma_f32_16x16x32_bf16(af, bn0, acc[a][0], 0, 0, 0);
      acc[a][1] = __builtin_amdgcn_mfma_f32_16x16x32_bf16(af, bn1, acc[a][1], 0, 0, 0);
    }
  };

  // fa2 = (L * T)[tid,:] — software-pipelined: issue edge e+1 reads, FMA edge e.
  f32x2 fa2[16];
  auto fma_edge = [&](float fv, uint4 qa, uint4 qb, uint4 qc, uint4 qd) {
    f32x2 fv2 = {fv, fv};
    u32 wq[16] = {qa.x, qa.y, qa.z, qa.w, qb.x, qb.y, qb.z, qb.w,
                  qc.x, qc.y, qc.z, qc.w, qd.x, qd.y, qd.z, qd.w};
#pragma unroll
    for (int p = 0; p < 16; ++p) {
      f32x2 s = {bflo(wq[p]), bfhi_raw(wq[p])};   // raw hi: <=2^-8 rel noise
      fa2[p] += fv2 * s;
    }
  };
  auto gather = [&](const u16* T) {
#pragma unroll
    for (int j = 0; j < 16; ++j) fa2[j] = (f32x2){0.f, 0.f};
    int trips = (trip + 1) & ~1;                  // even; padded edges have val 0
    int2 r0 = pp[0], r1 = pp[V], r2 = pp[2 * V];  // pair ring (e, e+1, e+2)
    const uint4* s0 = (const uint4*)((const char*)T + (u32)r0.x);
    uint4 A0 = s0[0], A1 = s0[1], A2 = s0[2], A3 = s0[3];
    for (int e = 0; e < trips; e += 2) {
      const uint4* s1 = (const uint4*)((const char*)T + (u32)r1.x);
      uint4 B0 = s1[0], B1 = s1[1], B2 = s1[2], B3 = s1[3];  // issue edge e+1
      int2 n3 = pp[(e + 3) * V];
      fma_edge(__int_as_float(r0.y), A0, A1, A2, A3);        // consume edge e
      const uint4* s2 = (const uint4*)((const char*)T + (u32)r2.x);
      A0 = s2[0]; A1 = s2[1]; A2 = s2[2]; A3 = s2[3];        // issue edge e+2
      int2 n4 = pp[(e + 4) * V];
      fma_edge(__int_as_float(r1.y), B0, B1, B2, B3);        // consume edge e+1
      r0 = r2; r1 = n3; r2 = n4;
    }
  };

  // update: write T_{k+1} into own row of `buf` (which holds T_{k-1}, read own-row only).
  // No barrier needed between gather and update: gather reads the OTHER buffer.
  auto do_update = [&](u16* buf, bool first) {
    uint4* bp = (uint4*)(buf + tid * ROWP);
    u32 npk[16];
    if (first) {
#pragma unroll
      for (int j = 0; j < 16; ++j) npk[j] = cvtpk_bf16(fa2[j][0], fa2[j][1]);
    } else {
      uint4 p0 = bp[0], p1 = bp[1], p2 = bp[2], p3 = bp[3];
      u32 wp[16] = {p0.x, p0.y, p0.z, p0.w, p1.x, p1.y, p1.z, p1.w,
                    p2.x, p2.y, p2.z, p2.w, p3.x, p3.y, p3.z, p3.w};
#pragma unroll
      for (int j = 0; j < 16; ++j) {
        float t0 = 2.f * fa2[j][0] - bflo(wp[j]);
        float t1 = 2.f * fa2[j][1] - bfhi(wp[j]);
        npk[j] = cvtpk_bf16(t0, t1);
      }
    }
#pragma unroll
    for (int j = 0; j < 4; ++j)
      bp[j] = make_uint4(npk[4 * j], npk[4 * j + 1], npk[4 * j + 2], npk[4 * j + 3]);
  };

  // ---- phases: gemm(T_k) ∥ gather(T_k) ∥ update other buffer; ONE barrier per phase
  gemm_acc(TA, 0);                 // TA=T0
  if (gath) { gather(TA); do_update(TB, true); }   // TB <- T1
  __syncthreads();
  gemm_acc(TB, 1);                 // TB=T1
  if (gath) { gather(TB); do_update(TA, false); }  // TA: T0 -> T2
  __syncthreads();
  gemm_acc(TA, 2);                 // TA=T2
  if (gath) { gather(TA); do_update(TB, false); }  // TB: T1 -> T3
  __syncthreads();
  gemm_acc(TB, 3);                 // TB=T3
  if (gath) { gather(TB); do_update(TA, false); }  // TA: T2 -> T4
  __syncthreads();
  gemm_acc(TA, 4);                 // TA=T4

  // ---- epilogue: pack (fout, fout+16) per lane -> bf16 stage[slice][v][l15]
  u32* stg = stage + (size_t)slice * (V * 16);
#pragma unroll
  for (int a = 0; a < 3; ++a) {
#pragma unroll
    for (int r = 0; r < 4; ++r) {
      int vr = PRM[w * 48 + a * 16 + l4 * 4 + r];
      u32 pk = cvtpk_bf16(acc[a][0][r] + bsv[0], acc[a][1][r] + bsv[1]);
      stg[vr * 16 + l15] = pk;
    }
  }
}

// ---------- kernel 5: stage [b][xyz][v][f2] bf16 -> out [b][fout][v][xyz] f32 ----------
#define TO_VT  12
#define TO_PAD 193
__global__ __launch_bounds__(512) void transpose_out(const u32* __restrict__ stage,
                                                     float* __restrict__ out) {
  __shared__ u32 T[64 * TO_PAD];   // 49.4 KB -> 2 blocks/CU
  int g = blockIdx.x;              // b(2) x vt(64) x xt(8)
  int b = g >> 9, vt = (g >> 3) & 63, xt = g & 7;
  int v0 = vt * TO_VT;
  int xyz0 = xt * 64;
  int t = threadIdx.x;
  const u32* base = stage + (size_t)(b * XYZ + xyz0) * (V * 16) + v0 * 16;
#pragma unroll
  for (int i = 0; i < 6; ++i) {
    int idx4 = i * 512 + t;
    int j = idx4 / 48;
    int c4 = idx4 - j * 48;
    uint4 q = *(const uint4*)(base + (size_t)j * (V * 16) + c4 * 4);
    int w0 = c4 * 4;
    T[j * TO_PAD + w0]     = q.x;
    T[j * TO_PAD + w0 + 1] = q.y;
    T[j * TO_PAD + w0 + 2] = q.z;
    T[j * TO_PAD + w0 + 3] = q.w;
  }
  __syncthreads();
  int xyz2 = t & 31;               // xyz pair: 2*xyz2, 2*xyz2+1
  int grp = t >> 5;                // 0..15
#pragma unroll
  for (int i = 0; i < 24; ++i) {
    int fout = grp * 2 + (i & 1);
    int vv = i >> 1;
    int col = vv * 16 + (fout & 15);
    u32 pka = T[(2 * xyz2) * TO_PAD + col];
    u32 pkb = T[(2 * xyz2 + 1) * TO_PAD + col];
    float va = (fout < 16) ? bflo(pka) : bfhi(pka);
    float vb = (fout < 16) ? bflo(pkb) : bfhi(pkb);
    *(float2*)&out[((size_t)(b * FOUTC + fout) * V + v0 + vv) * XYZ + xyz0 + 2 * xyz2] =
        make_float2(va, vb);
  }
}

extern "C" void kernel_launch(void* const* d_in, const int* in_sizes, int n_in,
                              void* d_out, int out_size, void* d_ws, size_t ws_size,
                              hipStream_t stream) {
  const int*   lap_rows = (const int*)d_in[0];
  const int*   lap_cols = (const int*)d_in[1];
  const float* lap_vals = (const float*)d_in[2];
  const float* x        = (const float*)d_in[3];
  const float* weight   = (const float*)d_in[4];
  const float* bias     = (const float*)d_in[5];
  float* out = (float*)d_out;
  int nnz = in_sizes[0];

  char* ws = (char*)d_ws;
  const size_t XT_BYTES = (size_t)NB * XYZ * V * FINC * sizeof(u16);  // 50,331,648
  const size_t EP_BYTES = (size_t)V * MAXDEG * 8;                     // 196,608
  const size_t E3_BYTES = (size_t)EROWS * V * 8;                      // 221,184
  u16*  xT    = (u16*)ws;                // aliased: bf16 stage [b][xyz][v][f2]
  u32*  stg   = (u32*)ws;
  int2* epair = (int2*)(ws + XT_BYTES);
  int2* ep3   = (int2*)(ws + XT_BYTES + EP_BYTES);
  int*  deg   = (int*)(ws + XT_BYTES + EP_BYTES + E3_BYTES);
  int*  perm  = (int*)(ws + XT_BYTES + EP_BYTES + E3_BYTES + 3072);
  int*  inv_g = (int*)(ws + XT_BYTES + EP_BYTES + E3_BYTES + 6144);
  int*  wtrip = (int*)(ws + XT_BYTES + EP_BYTES + E3_BYTES + 9216);

  hipLaunchKernelGGL(build_ell, dim3(V), dim3(64), 0, stream,
                     lap_rows, lap_cols, lap_vals, nnz, epair, deg);
  hipLaunchKernelGGL(sort_rows, dim3(1), dim3(V), 0, stream,
                     deg, perm, inv_g, wtrip);
  hipLaunchKernelGGL(transpose_x, dim3(NB * 64 * 8), dim3(512), 0, stream,
                     x, perm, deg, epair, inv_g, ep3, xT);
  hipLaunchKernelGGL(cheb_main, dim3(NB * XYZ), dim3(1024), 0, stream,
                     xT, ep3, perm, wtrip, weight, bias, stg);
  hipLaunchKernelGGL(transpose_out, dim3(NB * 64 * 8), dim3(512), 0, stream,
                     stg, out);
}

// Round 14
// 182.221 us; speedup vs baseline: 1.1752x; 1.0184x over previous
//
#include <hip/hip_runtime.h>
#include <stdint.h>

#define V      768
#define FINC   32
#define FOUTC  32
#define XYZ    512
#define NB     2
#define ROWP   40      // bf16 CUR row stride in ushorts (80 B)
#define QROW   48      // fp8 CURQ row stride in bytes
#define MAXDEG 32
#define EROWS  36      // transposed-ELL rows incl. 4-deep addr-prefetch pad

typedef unsigned short u16;
typedef unsigned int   u32;
typedef short bf16x8 __attribute__((ext_vector_type(8)));
typedef float f32x4  __attribute__((ext_vector_type(4)));
typedef float f32x2  __attribute__((ext_vector_type(2)));

__device__ __forceinline__ u16 f2bf(float f) {
  u32 u = __float_as_uint(f);
  u32 r = u + 0x7fffu + ((u >> 16) & 1u);   // RNE
  return (u16)(r >> 16);
}
__device__ __forceinline__ float bflo(u32 w) { return __uint_as_float(w << 16); }
__device__ __forceinline__ float bfhi(u32 w) { return __uint_as_float(w & 0xffff0000u); }
__device__ __forceinline__ u32 cvtpk_bf16(float lo, float hi) {
  u32 r;
  asm("v_cvt_pk_bf16_f32 %0, %1, %2" : "=v"(r) : "v"(lo), "v"(hi));
  return r;
}

// ---------- kernel 1: deterministic ELL build, interleaved (col,val), zero-padded ----------
__global__ __launch_bounds__(64) void build_ell(const int* __restrict__ rows,
                                                const int* __restrict__ cols,
                                                const float* __restrict__ vals,
                                                int nnz,
                                                int2* __restrict__ epair,
                                                int* __restrict__ deg) {
  int v = blockIdx.x;
  int lane = threadIdx.x;
  int cnt = 0;
  for (int base = 0; base < nnz; base += 64) {
    int i = base + lane;
    bool m = (i < nnz) && (rows[i] == v);
    unsigned long long mask = __ballot(m);
    if (m) {
      int pos = cnt + __popcll(mask & ((1ull << lane) - 1ull));
      if (pos < MAXDEG)
        epair[v * MAXDEG + pos] = make_int2(cols[i], __float_as_int(vals[i]));
    }
    cnt += __popcll(mask);
  }
  int d = cnt < MAXDEG ? cnt : MAXDEG;
  for (int p = d + lane; p < MAXDEG; p += 64)
    epair[v * MAXDEG + p] = make_int2(0, 0);
  if (lane == 0) deg[v] = d;
}

// ---------- kernel 2: degree sort + SIMD-balanced placement (rank/perm only) ----------
__global__ __launch_bounds__(V) void sort_rows(const int* __restrict__ deg,
                                               int* __restrict__ perm,
                                               int* __restrict__ inv_g,
                                               int* __restrict__ wtrip) {
  __shared__ int sdeg[V];
  int v = threadIdx.x;
  int d = deg[v];
  sdeg[v] = d;
  __syncthreads();
  int r = 0;                       // rank (desc degree, tie v asc)
  for (int u = 0; u < V; ++u) {
    int du = sdeg[u];
    r += (du > d) || (du == d && u < v);
  }
  // group gr=r>>6 -> wave GINV[gr]; nibble-packed GINV = {0,1,2,3,7,11,6,10,5,9,4,8}
  const unsigned long long GPK = 0x8495A6B73210ull;
  int w = (int)((GPK >> (4 * (r >> 6))) & 15ull);
  int p = w * 64 + (r & 63);
  perm[p] = v;
  inv_g[v] = p;
  if ((r & 63) == 0) wtrip[w] = d;
}

// ---------- kernel 3: x [B,Fin,V,XYZ] f32 -> xT [B,XYZ,pv,Fin] bf16 ----------
// LDS-tiled, both sides coalesced; float4 reads + cvt_pk_bf16.
// First EROWS blocks additionally build one transposed-ELL row each (fp8 byte offsets).
#define TXV 12
__global__ __launch_bounds__(512) void transpose_x(const float* __restrict__ x,
                                                   const int* __restrict__ perm,
                                                   const int* __restrict__ deg,
                                                   const int2* __restrict__ epair,
                                                   const int* __restrict__ inv_g,
                                                   int2* __restrict__ ep3,
                                                   u16* __restrict__ xT) {
  __shared__ u32 TL2[384 * 34];   // [pair(row)][xyz2], stride 34 u32 -> 2-way-free banks
  __shared__ int PV[TXV];
  int g = blockIdx.x;             // b(2) x pvt(64) x xt(8)
  int t = threadIdx.x;
  if (g < EROWS) {                // side-job: build ep3 row e=g
    int e = g;
    for (int p = t; p < V; p += 512) {
      int v = perm[p];
      int d = deg[v];
      int2 o = make_int2(0, 0);
      if (e < d) {                // e<d<=32 keeps epair access in-bounds
        int2 pe = epair[v * MAXDEG + e];
        o = make_int2(inv_g[pe.x] * QROW, pe.y);   // fp8 CURQ byte offset
      }
      ep3[e * V + p] = o;         // coalesced over p
    }
  }
  int b = g >> 9, pvt = (g >> 3) & 63, xt = g & 7;
  int pv0 = pvt * TXV;
  int xyz0 = xt * 64;
  if (t < TXV) PV[t] = perm[pv0 + t];
  __syncthreads();
  int q = t & 15;                 // xyz quad: 4q..4q+3
  int rgrp = t >> 4;              // 0..31
#pragma unroll
  for (int st = 0; st < 12; ++st) {
    int row = st * 32 + rgrp;     // pair index 0..383 = vloc*32 + f
    int vloc = row >> 5, f = row & 31;
    const float4 xv = *(const float4*)&x[((size_t)(b * FINC + f) * V + PV[vloc]) * XYZ + xyz0 + 4 * q];
    u32 A = cvtpk_bf16(xv.x, xv.y);
    u32 B = cvtpk_bf16(xv.z, xv.w);
    *(uint2*)&TL2[row * 34 + 2 * q] = make_uint2(A, B);
  }
  __syncthreads();
  const u16* TL16 = (const u16*)TL2;   // row stride 68 u16
  int s = t & 7, xyz = t >> 3;
  u32* dst = (u32*)(xT + ((size_t)(b * XYZ + xyz0 + xyz) * V + pv0) * FINC);
#pragma unroll
  for (int it = 0; it < 24; ++it) {
    int i = s + 8 * it;           // u32 index 0..191
    u32 lo = TL16[(2 * i) * 68 + xyz];
    u32 hi = TL16[(2 * i + 1) * 68 + xyz];
    dst[i] = lo | (hi << 16);
  }
}

// ---------- kernel 4: fused recursion + MFMA GEMM; pipelined fp8 gather ----------
__global__ __launch_bounds__(1024, 4) void cheb_main(
    const u16* __restrict__ xT, const int2* __restrict__ ep3,
    const int* __restrict__ perm, const int* __restrict__ wtrip,
    const float* __restrict__ weight, const float* __restrict__ bias,
    u32* __restrict__ stage) {
  __shared__ __align__(16) u16   CUR[V * ROWP];          // 61440 B (bf16, GEMM A)
  __shared__ __align__(16) unsigned char CURQ[V * QROW]; // 36864 B (fp8, gather)
  __shared__ __align__(16) uint4 WF[5][2][64];           // 10240 B
  __shared__ u16 PRM[V];
  __shared__ int WT[12];

  int g = blockIdx.x;
  int xcd = g & 7;
  int u = g >> 3;
  int phase = u >> 5;
  int xyz = xcd * 32 + (u & 31) + (phase & 1) * 256;
  int b = phase >> 1;
  int slice = b * XYZ + xyz;

  int tid = threadIdx.x;
  int lane = tid & 63;
  int w = tid >> 6;               // wave 0..15
  int l15 = lane & 15, l4 = lane >> 4;
  bool gath = tid < V;            // waves 0..11 gather/own rows

  if (tid < 640) {
    int k = tid >> 7, n = (tid >> 6) & 1, ln = tid & 63;
    int a15 = ln & 15, a4 = ln >> 4;
    u32 pw[4];
#pragma unroll
    for (int p = 0; p < 4; ++p) {
      float w0 = weight[(size_t)(k * FINC + a4 * 8 + 2 * p) * FOUTC + n * 16 + a15];
      float w1 = weight[(size_t)(k * FINC + a4 * 8 + 2 * p + 1) * FOUTC + n * 16 + a15];
      pw[p] = (u32)f2bf(w0) | ((u32)f2bf(w1) << 16);
    }
    WF[k][n][ln] = make_uint4(pw[0], pw[1], pw[2], pw[3]);
  }
  if (tid < 12) WT[tid] = wtrip[tid];
  if (gath) PRM[tid] = (u16)perm[tid];
  float bsv[2] = {bias[l15], bias[16 + l15]};

  // ---- load permuted slice row tid into CUR (bf16) + CURQ (fp8 shadow)
  if (gath) {
    const uint4* src = (const uint4*)(xT + (size_t)slice * V * FINC) + tid * 4;
    uint4* dst = (uint4*)(CUR + tid * ROWP);
    u32 cw[16], q8[8];
#pragma unroll
    for (int j = 0; j < 4; ++j) {
      uint4 q = src[j];
      dst[j] = q;
      cw[4 * j] = q.x; cw[4 * j + 1] = q.y;
      cw[4 * j + 2] = q.z; cw[4 * j + 3] = q.w;
    }
#pragma unroll
    for (int d = 0; d < 8; ++d) {
      u32 p0 = cw[2 * d], p1 = cw[2 * d + 1];
      u32 q = __builtin_amdgcn_cvt_pk_fp8_f32(bflo(p0), bfhi(p0), 0, false);
      q8[d] = __builtin_amdgcn_cvt_pk_fp8_f32(bflo(p1), bfhi(p1), q, true);
    }
    uint4* qp = (uint4*)(CURQ + tid * QROW);
    qp[0] = make_uint4(q8[0], q8[1], q8[2], q8[3]);
    qp[1] = make_uint4(q8[4], q8[5], q8[6], q8[7]);
  }
  __syncthreads();   // orders all xT reads before aliased stage writes at the end

  int trip = 0;
  if (w < 12) trip = __builtin_amdgcn_readfirstlane(WT[w]);
  const int2* pp = ep3 + tid;

  f32x4 acc[3][2];
#pragma unroll
  for (int a = 0; a < 3; ++a)
#pragma unroll
    for (int n = 0; n < 2; ++n) acc[a][n] = (f32x4){0.f, 0.f, 0.f, 0.f};

  // 16 waves x 48 rows each
  auto gemm_acc = [&](int k) {
    bf16x8 bn0 = *(const bf16x8*)&WF[k][0][lane];
    bf16x8 bn1 = *(const bf16x8*)&WF[k][1][lane];
#pragma unroll
    for (int a = 0; a < 3; ++a) {
      int row = w * 48 + a * 16 + l15;
      bf16x8 af = *(const bf16x8*)(CUR + row * ROWP + l4 * 8);
      acc[a][0] = __builtin_amdgcn_mfma_f32_16x16x32_bf16(af, bn0, acc[a][0], 0, 0, 0);
      acc[a][1] = __builtin_amdgcn_mfma_f32_16x16x32_bf16(af, bn1, acc[a][1], 0, 0, 0);
    }
  };

  // fa2 = (L * T)[tid,:] — fp8 rows (2 b128/edge), software-pipelined ring.
  f32x2 fa2[16];
  auto fma_edge8 = [&](float fv, uint4 qa, uint4 qb) {
    f32x2 fv2 = {fv, fv};
    u32 wq[8] = {qa.x, qa.y, qa.z, qa.w, qb.x, qb.y, qb.z, qb.w};
#pragma unroll
    for (int d = 0; d < 8; ++d) {
      f32x2 s0 = __builtin_amdgcn_cvt_pk_f32_fp8(wq[d], false);
      f32x2 s1 = __builtin_amdgcn_cvt_pk_f32_fp8(wq[d], true);
      fa2[2 * d]     += fv2 * s0;
      fa2[2 * d + 1] += fv2 * s1;
    }
  };
  auto gather = [&]() {
#pragma unroll
    for (int j = 0; j < 16; ++j) fa2[j] = (f32x2){0.f, 0.f};
    int trips = (trip + 1) & ~1;                  // even; padded edges have val 0
    int2 r0 = pp[0], r1 = pp[V], r2 = pp[2 * V];  // pair ring (e, e+1, e+2)
    const uint4* s0 = (const uint4*)(CURQ + (u32)r0.x);
    uint4 A0 = s0[0], A1 = s0[1];
    for (int e = 0; e < trips; e += 2) {
      const uint4* s1 = (const uint4*)(CURQ + (u32)r1.x);
      uint4 B0 = s1[0], B1 = s1[1];               // issue edge e+1
      int2 n3 = pp[(e + 3) * V];
      fma_edge8(__int_as_float(r0.y), A0, A1);    // consume edge e
      const uint4* s2 = (const uint4*)(CURQ + (u32)r2.x);
      A0 = s2[0]; A1 = s2[1];                     // issue edge e+2
      int2 n4 = pp[(e + 4) * V];
      fma_edge8(__int_as_float(r1.y), B0, B1);    // consume edge e+1
      r0 = r2; r1 = n3; r2 = n4;
    }
  };

  // prevpk regs hold bf16-packed T_{k-1}
  u32 prevpk[16];

  // ---- phases 0..3: gemm(T_k) ∥ gather(T_k) → barrier → update → barrier
#pragma unroll
  for (int ph = 0; ph <= 3; ++ph) {
    gemm_acc(ph);
    if (gath) gather();
    __syncthreads();
    if (gath) {
      uint4* cp = (uint4*)(CUR + tid * ROWP);
      uint4 c0 = cp[0], c1 = cp[1], c2 = cp[2], c3 = cp[3];   // T_k (own row)
      u32 cw[16] = {c0.x, c0.y, c0.z, c0.w, c1.x, c1.y, c1.z, c1.w,
                    c2.x, c2.y, c2.z, c2.w, c3.x, c3.y, c3.z, c3.w};
      u32 npk[16], q8[8];
      if (ph == 0) {
#pragma unroll
        for (int j = 0; j < 16; ++j) {
          float t0 = fa2[j][0], t1 = fa2[j][1];
          npk[j] = cvtpk_bf16(t0, t1);
          if ((j & 1) == 0) q8[j >> 1] = __builtin_amdgcn_cvt_pk_fp8_f32(t0, t1, 0, false);
          else              q8[j >> 1] = __builtin_amdgcn_cvt_pk_fp8_f32(t0, t1, q8[j >> 1], true);
        }
      } else {
#pragma unroll
        for (int j = 0; j < 16; ++j) {
          u32 pv = prevpk[j];
          float t0 = 2.f * fa2[j][0] - bflo(pv);
          float t1 = 2.f * fa2[j][1] - bfhi(pv);
          npk[j] = cvtpk_bf16(t0, t1);
          if ((j & 1) == 0) q8[j >> 1] = __builtin_amdgcn_cvt_pk_fp8_f32(t0, t1, 0, false);
          else              q8[j >> 1] = __builtin_amdgcn_cvt_pk_fp8_f32(t0, t1, q8[j >> 1], true);
        }
      }
#pragma unroll
      for (int j = 0; j < 16; ++j) prevpk[j] = cw[j];          // prev <- T_k
      cp[0] = make_uint4(npk[0], npk[1], npk[2], npk[3]);
      cp[1] = make_uint4(npk[4], npk[5], npk[6], npk[7]);
      cp[2] = make_uint4(npk[8], npk[9], npk[10], npk[11]);
      cp[3] = make_uint4(npk[12], npk[13], npk[14], npk[15]);
      uint4* qp = (uint4*)(CURQ + tid * QROW);
      qp[0] = make_uint4(q8[0], q8[1], q8[2], q8[3]);
      qp[1] = make_uint4(q8[4], q8[5], q8[6], q8[7]);
    }
    __syncthreads();
  }

  // ---- phase 4
  gemm_acc(4);

  // ---- epilogue: pack (fout, fout+16) per lane -> bf16 stage[slice][v][l15]
  u32* stg = stage + (size_t)slice * (V * 16);
#pragma unroll
  for (int a = 0; a < 3; ++a) {
#pragma unroll
    for (int r = 0; r < 4; ++r) {
      int vr = PRM[w * 48 + a * 16 + l4 * 4 + r];
      u32 pk = cvtpk_bf16(acc[a][0][r] + bsv[0], acc[a][1][r] + bsv[1]);
      stg[vr * 16 + l15] = pk;
    }
  }
}

// ---------- kernel 5: stage [b][xyz][v][f2] bf16 -> out [b][fout][v][xyz] f32 ----------
#define TO_VT  12
#define TO_PAD 193
__global__ __launch_bounds__(512) void transpose_out(const u32* __restrict__ stage,
                                                     float* __restrict__ out) {
  __shared__ u32 T[64 * TO_PAD];   // 49.4 KB -> 2 blocks/CU
  int g = blockIdx.x;              // b(2) x vt(64) x xt(8)
  int b = g >> 9, vt = (g >> 3) & 63, xt = g & 7;
  int v0 = vt * TO_VT;
  int xyz0 = xt * 64;
  int t = threadIdx.x;
  const u32* base = stage + (size_t)(b * XYZ + xyz0) * (V * 16) + v0 * 16;
#pragma unroll
  for (int i = 0; i < 6; ++i) {
    int idx4 = i * 512 + t;
    int j = idx4 / 48;
    int c4 = idx4 - j * 48;
    uint4 q = *(const uint4*)(base + (size_t)j * (V * 16) + c4 * 4);
    int w0 = c4 * 4;
    T[j * TO_PAD + w0]     = q.x;
    T[j * TO_PAD + w0 + 1] = q.y;
    T[j * TO_PAD + w0 + 2] = q.z;
    T[j * TO_PAD + w0 + 3] = q.w;
  }
  __syncthreads();
  int xyz2 = t & 31;               // xyz pair: 2*xyz2, 2*xyz2+1
  int grp = t >> 5;                // 0..15
#pragma unroll
  for (int i = 0; i < 24; ++i) {
    int fout = grp * 2 + (i & 1);
    int vv = i >> 1;
    int col = vv * 16 + (fout & 15);
    u32 pka = T[(2 * xyz2) * TO_PAD + col];
    u32 pkb = T[(2 * xyz2 + 1) * TO_PAD + col];
    float va = (fout < 16) ? bflo(pka) : bfhi(pka);
    float vb = (fout < 16) ? bflo(pkb) : bfhi(pkb);
    *(float2*)&out[((size_t)(b * FOUTC + fout) * V + v0 + vv) * XYZ + xyz0 + 2 * xyz2] =
        make_float2(va, vb);
  }
}

extern "C" void kernel_launch(void* const* d_in, const int* in_sizes, int n_in,
                              void* d_out, int out_size, void* d_ws, size_t ws_size,
                              hipStream_t stream) {
  const int*   lap_rows = (const int*)d_in[0];
  const int*   lap_cols = (const int*)d_in[1];
  const float* lap_vals = (const float*)d_in[2];
  const float* x        = (const float*)d_in[3];
  const float* weight   = (const float*)d_in[4];
  const float* bias     = (const float*)d_in[5];
  float* out = (float*)d_out;
  int nnz = in_sizes[0];

  char* ws = (char*)d_ws;
  const size_t XT_BYTES = (size_t)NB * XYZ * V * FINC * sizeof(u16);  // 50,331,648
  const size_t EP_BYTES = (size_t)V * MAXDEG * 8;                     // 196,608
  const size_t E3_BYTES = (size_t)EROWS * V * 8;                      // 221,184
  u16*  xT    = (u16*)ws;                // aliased: bf16 stage [b][xyz][v][f2]
  u32*  stg   = (u32*)ws;
  int2* epair = (int2*)(ws + XT_BYTES);
  int2* ep3   = (int2*)(ws + XT_BYTES + EP_BYTES);
  int*  deg   = (int*)(ws + XT_BYTES + EP_BYTES + E3_BYTES);
  int*  perm  = (int*)(ws + XT_BYTES + EP_BYTES + E3_BYTES + 3072);
  int*  inv_g = (int*)(ws + XT_BYTES + EP_BYTES + E3_BYTES + 6144);
  int*  wtrip = (int*)(ws + XT_BYTES + EP_BYTES + E3_BYTES + 9216);

  hipLaunchKernelGGL(build_ell, dim3(V), dim3(64), 0, stream,
                     lap_rows, lap_cols, lap_vals, nnz, epair, deg);
  hipLaunchKernelGGL(sort_rows, dim3(1), dim3(V), 0, stream,
                     deg, perm, inv_g, wtrip);
  hipLaunchKernelGGL(transpose_x, dim3(NB * 64 * 8), dim3(512), 0, stream,
                     x, perm, deg, epair, inv_g, ep3, xT);
  hipLaunchKernelGGL(cheb_main, dim3(NB * XYZ), dim3(1024), 0, stream,
                     xT, ep3, perm, wtrip, weight, bias, stg);
  hipLaunchKernelGGL(transpose_out, dim3(NB * 64 * 8), dim3(512), 0, stream,
                     stg, out);
}

// Round 15
// 181.289 us; speedup vs baseline: 1.1812x; 1.0051x over previous
//
#include <hip/hip_runtime.h>
#include <stdint.h>

#define V      768
#define FINC   32
#define FOUTC  32
#define XYZ    512
#define NB     2
#define ROWP   40      // bf16 CUR row stride in ushorts (80 B)
#define QROW   48      // fp8 CURQ row stride in bytes
#define MAXDEG 32
#define EROWS  36      // transposed-ELL rows incl. 4-deep addr-prefetch pad

typedef unsigned short u16;
typedef unsigned int   u32;
typedef short bf16x8 __attribute__((ext_vector_type(8)));
typedef float f32x4  __attribute__((ext_vector_type(4)));
typedef float f32x2  __attribute__((ext_vector_type(2)));

__device__ __forceinline__ u16 f2bf(float f) {
  u32 u = __float_as_uint(f);
  u32 r = u + 0x7fffu + ((u >> 16) & 1u);   // RNE
  return (u16)(r >> 16);
}
__device__ __forceinline__ float bflo(u32 w) { return __uint_as_float(w << 16); }
__device__ __forceinline__ float bfhi(u32 w) { return __uint_as_float(w & 0xffff0000u); }
__device__ __forceinline__ u32 cvtpk_bf16(float lo, float hi) {
  u32 r;
  asm("v_cvt_pk_bf16_f32 %0, %1, %2" : "=v"(r) : "v"(lo), "v"(hi));
  return r;
}

// ---------- kernel 1: prep — deg histogram + rank/perm/wtrip + ep3 zero-fill ----------
// Replaces build_ell+sort_rows launches. LDS int histogram: atomicAdd sums are
// order-independent -> deterministic. Rank identical to old sort_rows.
__global__ __launch_bounds__(1024) void prep(const int* __restrict__ rows, int nnz,
                                             int* __restrict__ perm,
                                             int* __restrict__ inv_g,
                                             int* __restrict__ wtrip,
                                             int2* __restrict__ ep3) {
  __shared__ int hist[V];
  int t = threadIdx.x;
  if (t < V) hist[t] = 0;
  __syncthreads();
  for (int i = t; i < nnz; i += 1024)
    atomicAdd(&hist[rows[i]], 1);
  __syncthreads();
  if (t < V) hist[t] = hist[t] < MAXDEG ? hist[t] : MAXDEG;   // clamped deg
  // zero ep3 (padded rows; real edges written by transpose_x side-job)
  for (int i = t; i < EROWS * V; i += 1024) ep3[i] = make_int2(0, 0);
  __syncthreads();
  if (t < V) {
    int d = hist[t];
    int r = 0;                     // rank (desc degree, tie v asc)
    for (int u = 0; u < V; ++u) {
      int du = hist[u];
      r += (du > d) || (du == d && u < t);
    }
    // group gr=r>>6 -> wave GINV[gr]; nibble-packed GINV = {0,1,2,3,7,11,6,10,5,9,4,8}
    const unsigned long long GPK = 0x8495A6B73210ull;
    int w = (int)((GPK >> (4 * (r >> 6))) & 15ull);
    int p = w * 64 + (r & 63);
    perm[p] = t;
    inv_g[t] = p;
    if ((r & 63) == 0) wtrip[w] = d;
  }
}

// ---------- kernel 2: x [B,Fin,V,XYZ] f32 -> xT [B,XYZ,pv,Fin] bf16 ----------
// LDS-tiled, both sides coalesced; float4 reads + cvt_pk_bf16.
// Wave 0 of blocks g<V additionally ELL-builds row g directly into ep3
// (same ballot-rank index order as the old build_ell -> bitwise-identical ELL).
#define TXV 12
__global__ __launch_bounds__(512) void transpose_x(const float* __restrict__ x,
                                                   const int* __restrict__ perm,
                                                   const int* __restrict__ inv_g,
                                                   const int* __restrict__ rows,
                                                   const int* __restrict__ cols,
                                                   const float* __restrict__ vals,
                                                   int nnz,
                                                   int2* __restrict__ ep3,
                                                   u16* __restrict__ xT) {
  __shared__ u32 TL2[384 * 34];   // [pair(row)][xyz2], stride 34 u32 -> 2-way-free banks
  __shared__ int PV[TXV];
  int g = blockIdx.x;             // b(2) x pvt(64) x xt(8)
  int t = threadIdx.x;
  int b = g >> 9, pvt = (g >> 3) & 63, xt = g & 7;
  int pv0 = pvt * TXV;
  int xyz0 = xt * 64;
  if (t < TXV) PV[t] = perm[pv0 + t];
  __syncthreads();
  int q = t & 15;                 // xyz quad: 4q..4q+3
  int rgrp = t >> 4;              // 0..31
#pragma unroll
  for (int st = 0; st < 12; ++st) {
    int row = st * 32 + rgrp;     // pair index 0..383 = vloc*32 + f
    int vloc = row >> 5, f = row & 31;
    const float4 xv = *(const float4*)&x[((size_t)(b * FINC + f) * V + PV[vloc]) * XYZ + xyz0 + 4 * q];
    u32 A = cvtpk_bf16(xv.x, xv.y);
    u32 B = cvtpk_bf16(xv.z, xv.w);
    *(uint2*)&TL2[row * 34 + 2 * q] = make_uint2(A, B);
  }
  __syncthreads();
  const u16* TL16 = (const u16*)TL2;   // row stride 68 u16
  int s = t & 7, xyz = t >> 3;
  u32* dst = (u32*)(xT + ((size_t)(b * XYZ + xyz0 + xyz) * V + pv0) * FINC);
#pragma unroll
  for (int it = 0; it < 24; ++it) {
    int i = s + 8 * it;           // u32 index 0..191
    u32 lo = TL16[(2 * i) * 68 + xyz];
    u32 hi = TL16[(2 * i + 1) * 68 + xyz];
    dst[i] = lo | (hi << 16);
  }
  // ---- side-job (wave 0, blocks g<V): ELL-build row g into ep3, fp8 byte offsets
  if (g < V && t < 64) {
    int v = g;
    int p = inv_g[v];
    int lane = t;
    int cnt = 0;
    for (int base = 0; base < nnz; base += 64) {
      int i = base + lane;
      bool m = (i < nnz) && (rows[i] == v);
      unsigned long long mask = __ballot(m);
      if (m) {
        int pos = cnt + __popcll(mask & ((1ull << lane) - 1ull));
        if (pos < MAXDEG)
          ep3[pos * V + p] = make_int2(inv_g[cols[i]] * QROW, __float_as_int(vals[i]));
      }
      cnt += __popcll(mask);
    }
  }
}

// ---------- kernel 3: fused recursion + MFMA GEMM; pipelined fp8 gather (r14) ----------
__global__ __launch_bounds__(1024, 4) void cheb_main(
    const u16* __restrict__ xT, const int2* __restrict__ ep3,
    const int* __restrict__ perm, const int* __restrict__ wtrip,
    const float* __restrict__ weight, const float* __restrict__ bias,
    u32* __restrict__ stage) {
  __shared__ __align__(16) u16   CUR[V * ROWP];          // 61440 B (bf16, GEMM A)
  __shared__ __align__(16) unsigned char CURQ[V * QROW]; // 36864 B (fp8, gather)
  __shared__ __align__(16) uint4 WF[5][2][64];           // 10240 B
  __shared__ u16 PRM[V];
  __shared__ int WT[12];

  int g = blockIdx.x;
  int xcd = g & 7;
  int u = g >> 3;
  int phase = u >> 5;
  int xyz = xcd * 32 + (u & 31) + (phase & 1) * 256;
  int b = phase >> 1;
  int slice = b * XYZ + xyz;

  int tid = threadIdx.x;
  int lane = tid & 63;
  int w = tid >> 6;               // wave 0..15
  int l15 = lane & 15, l4 = lane >> 4;
  bool gath = tid < V;            // waves 0..11 gather/own rows

  if (tid < 640) {
    int k = tid >> 7, n = (tid >> 6) & 1, ln = tid & 63;
    int a15 = ln & 15, a4 = ln >> 4;
    u32 pw[4];
#pragma unroll
    for (int p = 0; p < 4; ++p) {
      float w0 = weight[(size_t)(k * FINC + a4 * 8 + 2 * p) * FOUTC + n * 16 + a15];
      float w1 = weight[(size_t)(k * FINC + a4 * 8 + 2 * p + 1) * FOUTC + n * 16 + a15];
      pw[p] = (u32)f2bf(w0) | ((u32)f2bf(w1) << 16);
    }
    WF[k][n][ln] = make_uint4(pw[0], pw[1], pw[2], pw[3]);
  }
  if (tid < 12) WT[tid] = wtrip[tid];
  if (gath) PRM[tid] = (u16)perm[tid];
  float bsv[2] = {bias[l15], bias[16 + l15]};

  // ---- load permuted slice row tid into CUR (bf16) + CURQ (fp8 shadow)
  if (gath) {
    const uint4* src = (const uint4*)(xT + (size_t)slice * V * FINC) + tid * 4;
    uint4* dst = (uint4*)(CUR + tid * ROWP);
    u32 cw[16], q8[8];
#pragma unroll
    for (int j = 0; j < 4; ++j) {
      uint4 q = src[j];
      dst[j] = q;
      cw[4 * j] = q.x; cw[4 * j + 1] = q.y;
      cw[4 * j + 2] = q.z; cw[4 * j + 3] = q.w;
    }
#pragma unroll
    for (int d = 0; d < 8; ++d) {
      u32 p0 = cw[2 * d], p1 = cw[2 * d + 1];
      u32 q = __builtin_amdgcn_cvt_pk_fp8_f32(bflo(p0), bfhi(p0), 0, false);
      q8[d] = __builtin_amdgcn_cvt_pk_fp8_f32(bflo(p1), bfhi(p1), q, true);
    }
    uint4* qp = (uint4*)(CURQ + tid * QROW);
    qp[0] = make_uint4(q8[0], q8[1], q8[2], q8[3]);
    qp[1] = make_uint4(q8[4], q8[5], q8[6], q8[7]);
  }
  __syncthreads();   // orders all xT reads before aliased stage writes at the end

  int trip = 0;
  if (w < 12) trip = __builtin_amdgcn_readfirstlane(WT[w]);
  const int2* pp = ep3 + tid;

  f32x4 acc[3][2];
#pragma unroll
  for (int a = 0; a < 3; ++a)
#pragma unroll
    for (int n = 0; n < 2; ++n) acc[a][n] = (f32x4){0.f, 0.f, 0.f, 0.f};

  // 16 waves x 48 rows each
  auto gemm_acc = [&](int k) {
    bf16x8 bn0 = *(const bf16x8*)&WF[k][0][lane];
    bf16x8 bn1 = *(const bf16x8*)&WF[k][1][lane];
#pragma unroll
    for (int a = 0; a < 3; ++a) {
      int row = w * 48 + a * 16 + l15;
      bf16x8 af = *(const bf16x8*)(CUR + row * ROWP + l4 * 8);
      acc[a][0] = __builtin_amdgcn_mfma_f32_16x16x32_bf16(af, bn0, acc[a][0], 0, 0, 0);
      acc[a][1] = __builtin_amdgcn_mfma_f32_16x16x32_bf16(af, bn1, acc[a][1], 0, 0, 0);
    }
  };

  // fa2 = (L * T)[tid,:] — fp8 rows (2 b128/edge), software-pipelined ring.
  f32x2 fa2[16];
  auto fma_edge8 = [&](float fv, uint4 qa, uint4 qb) {
    f32x2 fv2 = {fv, fv};
    u32 wq[8] = {qa.x, qa.y, qa.z, qa.w, qb.x, qb.y, qb.z, qb.w};
#pragma unroll
    for (int d = 0; d < 8; ++d) {
      f32x2 s0 = __builtin_amdgcn_cvt_pk_f32_fp8(wq[d], false);
      f32x2 s1 = __builtin_amdgcn_cvt_pk_f32_fp8(wq[d], true);
      fa2[2 * d]     += fv2 * s0;
      fa2[2 * d + 1] += fv2 * s1;
    }
  };
  auto gather = [&]() {
#pragma unroll
    for (int j = 0; j < 16; ++j) fa2[j] = (f32x2){0.f, 0.f};
    int trips = (trip + 1) & ~1;                  // even; padded edges have val 0
    int2 r0 = pp[0], r1 = pp[V], r2 = pp[2 * V];  // pair ring (e, e+1, e+2)
    const uint4* s0 = (const uint4*)(CURQ + (u32)r0.x);
    uint4 A0 = s0[0], A1 = s0[1];
    for (int e = 0; e < trips; e += 2) {
      const uint4* s1 = (const uint4*)(CURQ + (u32)r1.x);
      uint4 B0 = s1[0], B1 = s1[1];               // issue edge e+1
      int2 n3 = pp[(e + 3) * V];
      fma_edge8(__int_as_float(r0.y), A0, A1);    // consume edge e
      const uint4* s2 = (const uint4*)(CURQ + (u32)r2.x);
      A0 = s2[0]; A1 = s2[1];                     // issue edge e+2
      int2 n4 = pp[(e + 4) * V];
      fma_edge8(__int_as_float(r1.y), B0, B1);    // consume edge e+1
      r0 = r2; r1 = n3; r2 = n4;
    }
  };

  // prevpk regs hold bf16-packed T_{k-1}
  u32 prevpk[16];

  // ---- phases 0..3: gemm(T_k) ∥ gather(T_k) → barrier → update → barrier
#pragma unroll
  for (int ph = 0; ph <= 3; ++ph) {
    gemm_acc(ph);
    if (gath) gather();
    __syncthreads();
    if (gath) {
      uint4* cp = (uint4*)(CUR + tid * ROWP);
      uint4 c0 = cp[0], c1 = cp[1], c2 = cp[2], c3 = cp[3];   // T_k (own row)
      u32 cw[16] = {c0.x, c0.y, c0.z, c0.w, c1.x, c1.y, c1.z, c1.w,
                    c2.x, c2.y, c2.z, c2.w, c3.x, c3.y, c3.z, c3.w};
      u32 npk[16], q8[8];
      if (ph == 0) {
#pragma unroll
        for (int j = 0; j < 16; ++j) {
          float t0 = fa2[j][0], t1 = fa2[j][1];
          npk[j] = cvtpk_bf16(t0, t1);
          if ((j & 1) == 0) q8[j >> 1] = __builtin_amdgcn_cvt_pk_fp8_f32(t0, t1, 0, false);
          else              q8[j >> 1] = __builtin_amdgcn_cvt_pk_fp8_f32(t0, t1, q8[j >> 1], true);
        }
      } else {
#pragma unroll
        for (int j = 0; j < 16; ++j) {
          u32 pv = prevpk[j];
          float t0 = 2.f * fa2[j][0] - bflo(pv);
          float t1 = 2.f * fa2[j][1] - bfhi(pv);
          npk[j] = cvtpk_bf16(t0, t1);
          if ((j & 1) == 0) q8[j >> 1] = __builtin_amdgcn_cvt_pk_fp8_f32(t0, t1, 0, false);
          else              q8[j >> 1] = __builtin_amdgcn_cvt_pk_fp8_f32(t0, t1, q8[j >> 1], true);
        }
      }
#pragma unroll
      for (int j = 0; j < 16; ++j) prevpk[j] = cw[j];          // prev <- T_k
      cp[0] = make_uint4(npk[0], npk[1], npk[2], npk[3]);
      cp[1] = make_uint4(npk[4], npk[5], npk[6], npk[7]);
      cp[2] = make_uint4(npk[8], npk[9], npk[10], npk[11]);
      cp[3] = make_uint4(npk[12], npk[13], npk[14], npk[15]);
      uint4* qp = (uint4*)(CURQ + tid * QROW);
      qp[0] = make_uint4(q8[0], q8[1], q8[2], q8[3]);
      qp[1] = make_uint4(q8[4], q8[5], q8[6], q8[7]);
    }
    __syncthreads();
  }

  // ---- phase 4
  gemm_acc(4);

  // ---- epilogue: pack (fout, fout+16) per lane -> bf16 stage[slice][v][l15]
  u32* stg = stage + (size_t)slice * (V * 16);
#pragma unroll
  for (int a = 0; a < 3; ++a) {
#pragma unroll
    for (int r = 0; r < 4; ++r) {
      int vr = PRM[w * 48 + a * 16 + l4 * 4 + r];
      u32 pk = cvtpk_bf16(acc[a][0][r] + bsv[0], acc[a][1][r] + bsv[1]);
      stg[vr * 16 + l15] = pk;
    }
  }
}

// ---------- kernel 4: stage [b][xyz][v][f2] bf16 -> out [b][fout][v][xyz] f32 ----------
#define TO_VT  12
#define TO_PAD 193
__global__ __launch_bounds__(512) void transpose_out(const u32* __restrict__ stage,
                                                     float* __restrict__ out) {
  __shared__ u32 T[64 * TO_PAD];   // 49.4 KB -> 2 blocks/CU
  int g = blockIdx.x;              // b(2) x vt(64) x xt(8)
  int b = g >> 9, vt = (g >> 3) & 63, xt = g & 7;
  int v0 = vt * TO_VT;
  int xyz0 = xt * 64;
  int t = threadIdx.x;
  const u32* base = stage + (size_t)(b * XYZ + xyz0) * (V * 16) + v0 * 16;
#pragma unroll
  for (int i = 0; i < 6; ++i) {
    int idx4 = i * 512 + t;
    int j = idx4 / 48;
    int c4 = idx4 - j * 48;
    uint4 q = *(const uint4*)(base + (size_t)j * (V * 16) + c4 * 4);
    int w0 = c4 * 4;
    T[j * TO_PAD + w0]     = q.x;
    T[j * TO_PAD + w0 + 1] = q.y;
    T[j * TO_PAD + w0 + 2] = q.z;
    T[j * TO_PAD + w0 + 3] = q.w;
  }
  __syncthreads();
  int xyz2 = t & 31;               // xyz pair: 2*xyz2, 2*xyz2+1
  int grp = t >> 5;                // 0..15
#pragma unroll
  for (int i = 0; i < 24; ++i) {
    int fout = grp * 2 + (i & 1);
    int vv = i >> 1;
    int col = vv * 16 + (fout & 15);
    u32 pka = T[(2 * xyz2) * TO_PAD + col];
    u32 pkb = T[(2 * xyz2 + 1) * TO_PAD + col];
    float va = (fout < 16) ? bflo(pka) : bfhi(pka);
    float vb = (fout < 16) ? bflo(pkb) : bfhi(pkb);
    *(float2*)&out[((size_t)(b * FOUTC + fout) * V + v0 + vv) * XYZ + xyz0 + 2 * xyz2] =
        make_float2(va, vb);
  }
}

extern "C" void kernel_launch(void* const* d_in, const int* in_sizes, int n_in,
                              void* d_out, int out_size, void* d_ws, size_t ws_size,
                              hipStream_t stream) {
  const int*   lap_rows = (const int*)d_in[0];
  const int*   lap_cols = (const int*)d_in[1];
  const float* lap_vals = (const float*)d_in[2];
  const float* x        = (const float*)d_in[3];
  const float* weight   = (const float*)d_in[4];
  const float* bias     = (const float*)d_in[5];
  float* out = (float*)d_out;
  int nnz = in_sizes[0];

  char* ws = (char*)d_ws;
  const size_t XT_BYTES = (size_t)NB * XYZ * V * FINC * sizeof(u16);  // 50,331,648
  const size_t E3_BYTES = (size_t)EROWS * V * 8;                      // 221,184
  u16*  xT    = (u16*)ws;                // aliased: bf16 stage [b][xyz][v][f2]
  u32*  stg   = (u32*)ws;
  int2* ep3   = (int2*)(ws + XT_BYTES);
  int*  perm  = (int*)(ws + XT_BYTES + E3_BYTES);
  int*  inv_g = (int*)(ws + XT_BYTES + E3_BYTES + 3072);
  int*  wtrip = (int*)(ws + XT_BYTES + E3_BYTES + 6144);

  hipLaunchKernelGGL(prep, dim3(1), dim3(1024), 0, stream,
                     lap_rows, nnz, perm, inv_g, wtrip, ep3);
  hipLaunchKernelGGL(transpose_x, dim3(NB * 64 * 8), dim3(512), 0, stream,
                     x, perm, inv_g, lap_rows, lap_cols, lap_vals, nnz, ep3, xT);
  hipLaunchKernelGGL(cheb_main, dim3(NB * XYZ), dim3(1024), 0, stream,
                     xT, ep3, perm, wtrip, weight, bias, stg);
  hipLaunchKernelGGL(transpose_out, dim3(NB * 64 * 8), dim3(512), 0, stream,
                     stg, out);
}

// Round 16
// 180.651 us; speedup vs baseline: 1.1854x; 1.0035x over previous
//
#include <hip/hip_runtime.h>
#include <stdint.h>

#define V      768
#define FINC   32
#define FOUTC  32
#define XYZ    512
#define NB     2
#define ROWP   40      // bf16 CUR row stride in ushorts (80 B)
#define QROW   48      // fp8 CURQ row stride in bytes
#define MAXDEG 32
#define EROWS  36      // transposed-ELL rows incl. 4-deep addr-prefetch pad

typedef unsigned short u16;
typedef unsigned int   u32;
typedef short bf16x8 __attribute__((ext_vector_type(8)));
typedef float f32x4  __attribute__((ext_vector_type(4)));
typedef float f32x2  __attribute__((ext_vector_type(2)));

__device__ __forceinline__ u16 f2bf(float f) {
  u32 u = __float_as_uint(f);
  u32 r = u + 0x7fffu + ((u >> 16) & 1u);   // RNE
  return (u16)(r >> 16);
}
__device__ __forceinline__ float bflo(u32 w) { return __uint_as_float(w << 16); }
__device__ __forceinline__ float bfhi(u32 w) { return __uint_as_float(w & 0xffff0000u); }
__device__ __forceinline__ u32 cvtpk_bf16(float lo, float hi) {
  u32 r;
  asm("v_cvt_pk_bf16_f32 %0, %1, %2" : "=v"(r) : "v"(lo), "v"(hi));
  return r;
}

// ---------- kernel 1: prep — deg histogram + rank/perm/wtrip + ep3 zero-fill ----------
__global__ __launch_bounds__(1024) void prep(const int* __restrict__ rows, int nnz,
                                             int* __restrict__ perm,
                                             int* __restrict__ inv_g,
                                             int* __restrict__ wtrip,
                                             int2* __restrict__ ep3) {
  __shared__ int hist[V];
  int t = threadIdx.x;
  if (t < V) hist[t] = 0;
  __syncthreads();
  for (int i = t; i < nnz; i += 1024)
    atomicAdd(&hist[rows[i]], 1);
  __syncthreads();
  if (t < V) hist[t] = hist[t] < MAXDEG ? hist[t] : MAXDEG;   // clamped deg
  for (int i = t; i < EROWS * V; i += 1024) ep3[i] = make_int2(0, 0);
  __syncthreads();
  if (t < V) {
    int d = hist[t];
    int r = 0;                     // rank (desc degree, tie v asc)
    for (int u = 0; u < V; ++u) {
      int du = hist[u];
      r += (du > d) || (du == d && u < t);
    }
    // group gr=r>>6 -> wave GINV[gr]; nibble-packed GINV = {0,1,2,3,7,11,6,10,5,9,4,8}
    const unsigned long long GPK = 0x8495A6B73210ull;
    int w = (int)((GPK >> (4 * (r >> 6))) & 15ull);
    int p = w * 64 + (r & 63);
    perm[p] = t;
    inv_g[t] = p;
    if ((r & 63) == 0) wtrip[w] = d;
  }
}

// ---------- kernel 2: x [B,Fin,V,XYZ] f32 -> xT [B,XYZ,pv,Fin] bf16 ----------
// LDS-tiled, both sides coalesced; float4 reads + cvt_pk_bf16; uint4 stores.
// Wave 0 of blocks g<V additionally ELL-builds row g directly into ep3.
#define TXV 12
__global__ __launch_bounds__(512) void transpose_x(const float* __restrict__ x,
                                                   const int* __restrict__ perm,
                                                   const int* __restrict__ inv_g,
                                                   const int* __restrict__ rows,
                                                   const int* __restrict__ cols,
                                                   const float* __restrict__ vals,
                                                   int nnz,
                                                   int2* __restrict__ ep3,
                                                   u16* __restrict__ xT) {
  __shared__ u32 TL2[384 * 34];   // [pair(row)][xyz2], stride 34 u32 -> 2-way-free banks
  __shared__ int PV[TXV];
  int g = blockIdx.x;             // b(2) x pvt(64) x xt(8)
  int t = threadIdx.x;
  int b = g >> 9, pvt = (g >> 3) & 63, xt = g & 7;
  int pv0 = pvt * TXV;
  int xyz0 = xt * 64;
  if (t < TXV) PV[t] = perm[pv0 + t];
  __syncthreads();
  int q = t & 15;                 // xyz quad: 4q..4q+3
  int rgrp = t >> 4;              // 0..31
#pragma unroll
  for (int st = 0; st < 12; ++st) {
    int row = st * 32 + rgrp;     // pair index 0..383 = vloc*32 + f
    int vloc = row >> 5, f = row & 31;
    const float4 xv = *(const float4*)&x[((size_t)(b * FINC + f) * V + PV[vloc]) * XYZ + xyz0 + 4 * q];
    u32 A = cvtpk_bf16(xv.x, xv.y);
    u32 B = cvtpk_bf16(xv.z, xv.w);
    *(uint2*)&TL2[row * 34 + 2 * q] = make_uint2(A, B);
  }
  __syncthreads();
  const u16* TL16 = (const u16*)TL2;   // row stride 68 u16
  int c = t & 7, xyz = t >> 3;
  uint4* dst4 = (uint4*)(xT + ((size_t)(b * XYZ + xyz0 + xyz) * V + pv0) * FINC);
#pragma unroll
  for (int it = 0; it < 6; ++it) {
    int ci = c + 8 * it;          // uint4 index 0..47
    u32 wv[4];
#pragma unroll
    for (int j = 0; j < 4; ++j) {
      int i = 4 * ci + j;         // u32 index 0..191
      u32 lo = TL16[(2 * i) * 68 + xyz];
      u32 hi = TL16[(2 * i + 1) * 68 + xyz];
      wv[j] = lo | (hi << 16);
    }
    dst4[ci] = make_uint4(wv[0], wv[1], wv[2], wv[3]);   // 128B contiguous per 8 lanes
  }
  // ---- side-job (wave 0, blocks g<V): ELL-build row g into ep3, fp8 byte offsets
  if (g < V && t < 64) {
    int v = g;
    int p = inv_g[v];
    int lane = t;
    int cnt = 0;
    for (int base = 0; base < nnz; base += 64) {
      int i = base + lane;
      bool m = (i < nnz) && (rows[i] == v);
      unsigned long long mask = __ballot(m);
      if (m) {
        int pos = cnt + __popcll(mask & ((1ull << lane) - 1ull));
        if (pos < MAXDEG)
          ep3[pos * V + p] = make_int2(inv_g[cols[i]] * QROW, __float_as_int(vals[i]));
      }
      cnt += __popcll(mask);
    }
  }
}

// ---------- kernel 3: fused recursion + MFMA GEMM; pipelined fp8 gather (r14) ----------
__global__ __launch_bounds__(1024, 4) void cheb_main(
    const u16* __restrict__ xT, const int2* __restrict__ ep3,
    const int* __restrict__ perm, const int* __restrict__ wtrip,
    const float* __restrict__ weight, const float* __restrict__ bias,
    u32* __restrict__ stage) {
  __shared__ __align__(16) u16   CUR[V * ROWP];          // 61440 B (bf16, GEMM A)
  __shared__ __align__(16) unsigned char CURQ[V * QROW]; // 36864 B (fp8, gather)
  __shared__ __align__(16) uint4 WF[5][2][64];           // 10240 B
  __shared__ u16 PRM[V];
  __shared__ int WT[12];

  int g = blockIdx.x;
  int xcd = g & 7;
  int u = g >> 3;
  int phase = u >> 5;
  int xyz = xcd * 32 + (u & 31) + (phase & 1) * 256;
  int b = phase >> 1;
  int slice = b * XYZ + xyz;

  int tid = threadIdx.x;
  int lane = tid & 63;
  int w = tid >> 6;               // wave 0..15
  int l15 = lane & 15, l4 = lane >> 4;
  bool gath = tid < V;            // waves 0..11 gather/own rows

  if (tid < 640) {
    int k = tid >> 7, n = (tid >> 6) & 1, ln = tid & 63;
    int a15 = ln & 15, a4 = ln >> 4;
    u32 pw[4];
#pragma unroll
    for (int p = 0; p < 4; ++p) {
      float w0 = weight[(size_t)(k * FINC + a4 * 8 + 2 * p) * FOUTC + n * 16 + a15];
      float w1 = weight[(size_t)(k * FINC + a4 * 8 + 2 * p + 1) * FOUTC + n * 16 + a15];
      pw[p] = (u32)f2bf(w0) | ((u32)f2bf(w1) << 16);
    }
    WF[k][n][ln] = make_uint4(pw[0], pw[1], pw[2], pw[3]);
  }
  if (tid < 12) WT[tid] = wtrip[tid];
  if (gath) PRM[tid] = (u16)perm[tid];
  float bsv[2] = {bias[l15], bias[16 + l15]};

  // ---- load permuted slice row tid into CUR (bf16) + CURQ (fp8 shadow)
  if (gath) {
    const uint4* src = (const uint4*)(xT + (size_t)slice * V * FINC) + tid * 4;
    uint4* dst = (uint4*)(CUR + tid * ROWP);
    u32 cw[16], q8[8];
#pragma unroll
    for (int j = 0; j < 4; ++j) {
      uint4 q = src[j];
      dst[j] = q;
      cw[4 * j] = q.x; cw[4 * j + 1] = q.y;
      cw[4 * j + 2] = q.z; cw[4 * j + 3] = q.w;
    }
#pragma unroll
    for (int d = 0; d < 8; ++d) {
      u32 p0 = cw[2 * d], p1 = cw[2 * d + 1];
      u32 q = __builtin_amdgcn_cvt_pk_fp8_f32(bflo(p0), bfhi(p0), 0, false);
      q8[d] = __builtin_amdgcn_cvt_pk_fp8_f32(bflo(p1), bfhi(p1), q, true);
    }
    uint4* qp = (uint4*)(CURQ + tid * QROW);
    qp[0] = make_uint4(q8[0], q8[1], q8[2], q8[3]);
    qp[1] = make_uint4(q8[4], q8[5], q8[6], q8[7]);
  }
  __syncthreads();   // orders all xT reads before aliased stage writes at the end

  int trip = 0;
  if (w < 12) trip = __builtin_amdgcn_readfirstlane(WT[w]);
  const int2* pp = ep3 + tid;

  f32x4 acc[3][2];
#pragma unroll
  for (int a = 0; a < 3; ++a)
#pragma unroll
    for (int n = 0; n < 2; ++n) acc[a][n] = (f32x4){0.f, 0.f, 0.f, 0.f};

  // 16 waves x 48 rows each
  auto gemm_acc = [&](int k) {
    bf16x8 bn0 = *(const bf16x8*)&WF[k][0][lane];
    bf16x8 bn1 = *(const bf16x8*)&WF[k][1][lane];
#pragma unroll
    for (int a = 0; a < 3; ++a) {
      int row = w * 48 + a * 16 + l15;
      bf16x8 af = *(const bf16x8*)(CUR + row * ROWP + l4 * 8);
      acc[a][0] = __builtin_amdgcn_mfma_f32_16x16x32_bf16(af, bn0, acc[a][0], 0, 0, 0);
      acc[a][1] = __builtin_amdgcn_mfma_f32_16x16x32_bf16(af, bn1, acc[a][1], 0, 0, 0);
    }
  };

  // fa2 = (L * T)[tid,:] — fp8 rows (2 b128/edge), software-pipelined ring.
  f32x2 fa2[16];
  auto fma_edge8 = [&](float fv, uint4 qa, uint4 qb) {
    f32x2 fv2 = {fv, fv};
    u32 wq[8] = {qa.x, qa.y, qa.z, qa.w, qb.x, qb.y, qb.z, qb.w};
#pragma unroll
    for (int d = 0; d < 8; ++d) {
      f32x2 s0 = __builtin_amdgcn_cvt_pk_f32_fp8(wq[d], false);
      f32x2 s1 = __builtin_amdgcn_cvt_pk_f32_fp8(wq[d], true);
      fa2[2 * d]     += fv2 * s0;
      fa2[2 * d + 1] += fv2 * s1;
    }
  };
  auto gather = [&]() {
#pragma unroll
    for (int j = 0; j < 16; ++j) fa2[j] = (f32x2){0.f, 0.f};
    int trips = (trip + 1) & ~1;                  // even; padded edges have val 0
    int2 r0 = pp[0], r1 = pp[V], r2 = pp[2 * V];  // pair ring (e, e+1, e+2)
    const uint4* s0 = (const uint4*)(CURQ + (u32)r0.x);
    uint4 A0 = s0[0], A1 = s0[1];
    for (int e = 0; e < trips; e += 2) {
      const uint4* s1 = (const uint4*)(CURQ + (u32)r1.x);
      uint4 B0 = s1[0], B1 = s1[1];               // issue edge e+1
      int2 n3 = pp[(e + 3) * V];
      fma_edge8(__int_as_float(r0.y), A0, A1);    // consume edge e
      const uint4* s2 = (const uint4*)(CURQ + (u32)r2.x);
      A0 = s2[0]; A1 = s2[1];                     // issue edge e+2
      int2 n4 = pp[(e + 4) * V];
      fma_edge8(__int_as_float(r1.y), B0, B1);    // consume edge e+1
      r0 = r2; r1 = n3; r2 = n4;
    }
  };

  // prevpk regs hold bf16-packed T_{k-1}
  u32 prevpk[16];

  // ---- phases 0..3: gemm(T_k) ∥ gather(T_k) → barrier → update → barrier
#pragma unroll
  for (int ph = 0; ph <= 3; ++ph) {
    gemm_acc(ph);
    if (gath) gather();
    __syncthreads();
    if (gath) {
      uint4* cp = (uint4*)(CUR + tid * ROWP);
      uint4 c0 = cp[0], c1 = cp[1], c2 = cp[2], c3 = cp[3];   // T_k (own row)
      u32 cw[16] = {c0.x, c0.y, c0.z, c0.w, c1.x, c1.y, c1.z, c1.w,
                    c2.x, c2.y, c2.z, c2.w, c3.x, c3.y, c3.z, c3.w};
      u32 npk[16], q8[8];
      if (ph == 0) {
#pragma unroll
        for (int j = 0; j < 16; ++j) {
          float t0 = fa2[j][0], t1 = fa2[j][1];
          npk[j] = cvtpk_bf16(t0, t1);
          if ((j & 1) == 0) q8[j >> 1] = __builtin_amdgcn_cvt_pk_fp8_f32(t0, t1, 0, false);
          else              q8[j >> 1] = __builtin_amdgcn_cvt_pk_fp8_f32(t0, t1, q8[j >> 1], true);
        }
      } else {
#pragma unroll
        for (int j = 0; j < 16; ++j) {
          u32 pv = prevpk[j];
          float t0 = 2.f * fa2[j][0] - bflo(pv);
          float t1 = 2.f * fa2[j][1] - bfhi(pv);
          npk[j] = cvtpk_bf16(t0, t1);
          if ((j & 1) == 0) q8[j >> 1] = __builtin_amdgcn_cvt_pk_fp8_f32(t0, t1, 0, false);
          else              q8[j >> 1] = __builtin_amdgcn_cvt_pk_fp8_f32(t0, t1, q8[j >> 1], true);
        }
      }
#pragma unroll
      for (int j = 0; j < 16; ++j) prevpk[j] = cw[j];          // prev <- T_k
      cp[0] = make_uint4(npk[0], npk[1], npk[2], npk[3]);
      cp[1] = make_uint4(npk[4], npk[5], npk[6], npk[7]);
      cp[2] = make_uint4(npk[8], npk[9], npk[10], npk[11]);
      cp[3] = make_uint4(npk[12], npk[13], npk[14], npk[15]);
      uint4* qp = (uint4*)(CURQ + tid * QROW);
      qp[0] = make_uint4(q8[0], q8[1], q8[2], q8[3]);
      qp[1] = make_uint4(q8[4], q8[5], q8[6], q8[7]);
    }
    __syncthreads();
  }

  // ---- phase 4
  gemm_acc(4);

  // ---- epilogue: pack (fout, fout+16) per lane -> bf16 stage[slice][v][l15]
  u32* stg = stage + (size_t)slice * (V * 16);
#pragma unroll
  for (int a = 0; a < 3; ++a) {
#pragma unroll
    for (int r = 0; r < 4; ++r) {
      int vr = PRM[w * 48 + a * 16 + l4 * 4 + r];
      u32 pk = cvtpk_bf16(acc[a][0][r] + bsv[0], acc[a][1][r] + bsv[1]);
      stg[vr * 16 + l15] = pk;
    }
  }
}

// ---------- kernel 4: stage [b][xyz][v][f2] bf16 -> out [b][fout][v][xyz] f32 ----------
#define TO_VT  12
#define TO_PAD 193
__global__ __launch_bounds__(512) void transpose_out(const u32* __restrict__ stage,
                                                     float* __restrict__ out) {
  __shared__ u32 T[64 * TO_PAD];   // 49.4 KB -> 2 blocks/CU
  int g = blockIdx.x;              // b(2) x vt(64) x xt(8)
  int b = g >> 9, vt = (g >> 3) & 63, xt = g & 7;
  int v0 = vt * TO_VT;
  int xyz0 = xt * 64;
  int t = threadIdx.x;
  const u32* base = stage + (size_t)(b * XYZ + xyz0) * (V * 16) + v0 * 16;
#pragma unroll
  for (int i = 0; i < 6; ++i) {
    int idx4 = i * 512 + t;
    int j = idx4 / 48;
    int c4 = idx4 - j * 48;
    uint4 q = *(const uint4*)(base + (size_t)j * (V * 16) + c4 * 4);
    int w0 = c4 * 4;
    T[j * TO_PAD + w0]     = q.x;
    T[j * TO_PAD + w0 + 1] = q.y;
    T[j * TO_PAD + w0 + 2] = q.z;
    T[j * TO_PAD + w0 + 3] = q.w;
  }
  __syncthreads();
  int x4 = (t & 15) * 4;           // xyz quad
  int fout = t >> 4;               // 0..31 (wave-uniform fout<16 predicate)
#pragma unroll
  for (int vv = 0; vv < TO_VT; ++vv) {
    int col = vv * 16 + (fout & 15);
    u32 p0 = T[(x4)     * TO_PAD + col];
    u32 p1 = T[(x4 + 1) * TO_PAD + col];
    u32 p2 = T[(x4 + 2) * TO_PAD + col];
    u32 p3 = T[(x4 + 3) * TO_PAD + col];
    float4 o;
    if (fout < 16) o = make_float4(bflo(p0), bflo(p1), bflo(p2), bflo(p3));
    else           o = make_float4(bfhi(p0), bfhi(p1), bfhi(p2), bfhi(p3));
    *(float4*)&out[((size_t)(b * FOUTC + fout) * V + v0 + vv) * XYZ + xyz0 + x4] = o;
  }
}

extern "C" void kernel_launch(void* const* d_in, const int* in_sizes, int n_in,
                              void* d_out, int out_size, void* d_ws, size_t ws_size,
                              hipStream_t stream) {
  const int*   lap_rows = (const int*)d_in[0];
  const int*   lap_cols = (const int*)d_in[1];
  const float* lap_vals = (const float*)d_in[2];
  const float* x        = (const float*)d_in[3];
  const float* weight   = (const float*)d_in[4];
  const float* bias     = (const float*)d_in[5];
  float* out = (float*)d_out;
  int nnz = in_sizes[0];

  char* ws = (char*)d_ws;
  const size_t XT_BYTES = (size_t)NB * XYZ * V * FINC * sizeof(u16);  // 50,331,648
  const size_t E3_BYTES = (size_t)EROWS * V * 8;                      // 221,184
  u16*  xT    = (u16*)ws;                // aliased: bf16 stage [b][xyz][v][f2]
  u32*  stg   = (u32*)ws;
  int2* ep3   = (int2*)(ws + XT_BYTES);
  int*  perm  = (int*)(ws + XT_BYTES + E3_BYTES);
  int*  inv_g = (int*)(ws + XT_BYTES + E3_BYTES + 3072);
  int*  wtrip = (int*)(ws + XT_BYTES + E3_BYTES + 6144);

  hipLaunchKernelGGL(prep, dim3(1), dim3(1024), 0, stream,
                     lap_rows, nnz, perm, inv_g, wtrip, ep3);
  hipLaunchKernelGGL(transpose_x, dim3(NB * 64 * 8), dim3(512), 0, stream,
                     x, perm, inv_g, lap_rows, lap_cols, lap_vals, nnz, ep3, xT);
  hipLaunchKernelGGL(cheb_main, dim3(NB * XYZ), dim3(1024), 0, stream,
                     xT, ep3, perm, wtrip, weight, bias, stg);
  hipLaunchKernelGGL(transpose_out, dim3(NB * 64 * 8), dim3(512), 0, stream,
                     stg, out);
}